// Round 12
// baseline (219.433 us; speedup 1.0000x reference)
//
#include <hip/hip_runtime.h>
#include <math.h>

// B=8, L=32, H=1024, N=32
// ws layout (floats):
#define NODE_OFF   0          // 8192*32
#define SPAN_OFF   262144     // 8192
#define D_OFF      270336     // 256*32
#define RBF_OFF    278528     // 32768 halfs: frag-order bf16 exp(rules)

typedef short bf16x8 __attribute__((ext_vector_type(8)));
typedef float f32x16 __attribute__((ext_vector_type(16)));

union BFU { unsigned u[4]; bf16x8 v; };

__device__ inline short f2bf(float f) {            // RNE f32->bf16
  union { float f; unsigned u; } v; v.f = f;
  unsigned r = (v.u + 0x7FFFu + ((v.u >> 16) & 1u)) >> 16;
  return (short)r;
}
__device__ __forceinline__ unsigned short hubf(float f) {  // half-up round (2 ops)
  return (unsigned short)((__float_as_uint(f) + 0x8000u) >> 16);
}

// Fused front kernel, 640 blocks x 256:
//  0..255: node full-K GEMM (32 rows/block) + span
//  256..511: posnode + D
//  512..639: Rbf swizzle
__global__ __launch_bounds__(256) void k_front(
    const float* __restrict__ ph, const float* __restrict__ Wn,
    const float* __restrict__ bn, const float* __restrict__ Ws,
    const float* __restrict__ bs, const float* __restrict__ sh,
    const float* __restrict__ Wp, const float* __restrict__ bp,
    const float* __restrict__ pmask, const float* __restrict__ pu,
    const float* __restrict__ pum, const float* __restrict__ rs,
    const float* __restrict__ rm, float* __restrict__ node,
    float* __restrict__ span, float* __restrict__ D,
    unsigned short* __restrict__ Rbf) {
  __shared__ float smem[8448];
  int t = threadIdx.x;
  int bid = blockIdx.x;
  if (bid >= 512) {   // ---- Rbf: frag-order bf16 of exp(masked rules) ----
    int idx = ((bid - 512) << 8) + t;        // [kst(64)][lane(64)][r(8)]
    int kst = idx >> 9, ln = (idx >> 3) & 63, r = idx & 7;
    int a = ln & 31;
    int kp = kst * 16 + ((ln >> 5) << 3) + r;   // k' = p*32+q
    float v = __expf(rs[a * 1024 + kp] + (rm[a * 1024 + kp] - 1.0f) * 1e10f);
    Rbf[idx] = (unsigned short)f2bf(v);
    return;
  }
  if (bid >= 256) {   // ---- posnode + D ----
    float* rowl = smem;
    float* partl = smem + 1024;
    float* posn = smem + 1288;
    int row = bid - 256;
#pragma unroll
    for (int k = 0; k < 4; ++k) rowl[t + 256 * k] = sh[row * 1024 + t + 256 * k];
    __syncthreads();
    int c = t & 31, seg = t >> 5;
    float pacc = 0.f;
    for (int hh = 0; hh < 128; ++hh)
      pacc += rowl[seg * 128 + hh] * Wp[(seg * 128 + hh) * 32 + c];
    partl[seg * 33 + c] = pacc;
    __syncthreads();
    if (t < 32) {
      float s = 0.f;
#pragma unroll
      for (int k = 0; k < 8; ++k) s += partl[k * 33 + t];
      posn[t] = s + bp[t] + (pmask[t] - 1.0f) * 1e10f;
    }
    __syncthreads();
    if (t < 32) {
      float mq = posn[t];
#pragma unroll
      for (int m = 16; m >= 1; m >>= 1) mq = fmaxf(mq, __shfl_xor(mq, m, 32));
      float sum = 0.f;
#pragma unroll 8
      for (int q = 0; q < 32; ++q)
        sum += __expf(pu[t * 32 + q] + (pum[t * 32 + q] - 1.0f) * 1e15f + posn[q] - mq);
      D[row * 32 + t] = mq + __logf(sum);
    }
    return;
  }
  // ---- node full-K GEMM: 32 rows, K=1024, 32 cols; thread = 1 row x 4 cols ----
  float (*A)[132] = (float(*)[132])smem;            // 32x132
  float (*Wl)[32] = (float(*)[32])(smem + 4224);    // 128x32
  float* Wsl = smem + 8320;                         // 128
  int row0 = bid * 32;
  int r = t >> 3, tc = t & 7, c = tc << 2;
  float acc0 = 0.f, acc1 = 0.f, acc2 = 0.f, acc3 = 0.f, sp = 0.f;
  for (int hc = 0; hc < 8; ++hc) {
    int hb = hc << 7;
#pragma unroll
    for (int k = 0; k < 4; ++k) {          // A: 32x128 f32 = 1024 float4
      int f = t + (k << 8);
      int rr = f >> 5, c4 = f & 31;
      *(float4*)&A[rr][c4 << 2] =
          *(const float4*)&ph[(row0 + rr) * 1024 + hb + (c4 << 2)];
    }
#pragma unroll
    for (int k = 0; k < 4; ++k) {          // W: 128x32 f32 = 1024 float4
      int f = t + (k << 8);
      int hh = f >> 3, c4 = f & 7;
      *(float4*)&Wl[hh][c4 << 2] =
          *(const float4*)&Wn[(hb + hh) * 32 + (c4 << 2)];
    }
    if (t < 128) Wsl[t] = Ws[hb + t];
    __syncthreads();
#pragma unroll 2
    for (int h = 0; h < 128; ++h) {
      float a0 = A[r][h];
      float4 wv = *(const float4*)&Wl[h][c];
      acc0 += a0 * wv.x; acc1 += a0 * wv.y; acc2 += a0 * wv.z; acc3 += a0 * wv.w;
      if (tc == 0) sp += a0 * Wsl[h];
    }
    __syncthreads();
  }
  int row = row0 + r;
  *(float4*)&node[row * 32 + c] =
      make_float4(acc0 + bn[c], acc1 + bn[c + 1], acc2 + bn[c + 2], acc3 + bn[c + 3]);
  if (tc == 0) span[row] = sp + bs[0];
}

// One block per batch; chart as NORMALIZED X = exp(cn - rowmax) in LDS
// (transposed [symbol][cellidx], stride 529). Per stage (3 barriers):
// [preamble tables (in-wave) + P2] B1 [P3] B2 [out+renorm] B3
// LDS 152512 B:
//   Xt    f32[32*529]   @0
//   Sb    32 x 2052 B   @67712    (bf16 S, XOR-swizzled)
//   slots f32[4*1056]   @133376   (cell-major, stride 33)
//   maxv  f32[528]      @150272
//   G     f32[32]       @152384
__global__ __launch_bounds__(1024) void k_chain7(
    const float* __restrict__ node, const float* __restrict__ span,
    const float* __restrict__ D, const unsigned short* __restrict__ Rbf,
    const int* __restrict__ sm, const float* __restrict__ rootm,
    float* __restrict__ out) {
  extern __shared__ char lds[];
  float* Xt = (float*)lds;
  char* Sb = lds + 67712;
  float* slots = (float*)(lds + 133376);
  float* maxv = (float*)(lds + 150272);
  float* G = (float*)(lds + 152384);
  const int t = threadIdx.x;
  const int b = blockIdx.x;
  const int w = t >> 6, ln = t & 63;
  const int pq = ln & 31, hi = ln >> 5, jb = hi << 3;
  const int rowB = b * 32;

  // ---- zero-init Xt (NaN-proof) + diagonal init from node & D ----
  {
    int l = t >> 5, a = t & 31;
    float nd = node[(rowB + l) * 1024 + l * 32 + a];   // prefetch overlaps memset
    float Dv = D[(rowB + l) * 32 + a];
    float* z = (float*)lds;
    for (int idx = t; idx < 16928; idx += 1024) z[idx] = 0.f;
    __syncthreads();
    float dv = nd + nd + Dv;                           // chart_diag + node
    float m = dv;
#pragma unroll
    for (int s = 16; s >= 1; s >>= 1) m = fmaxf(m, __shfl_xor(m, s, 32));
    int off = l * (65 - l) / 2;
    Xt[a * 529 + off] = __expf(dv - m);
    if (a == 0) maxv[off] = m;
  }
  __syncthreads();

  for (int i = 1; i < 32; ++i) {
    const int nT = 32 - i;
    // ---- out-phase operand prefetch (mapping: cell=t>>5, a=t&31) ----
    float nv = 0.f, sv = 0.f;
    {
      int cell = t >> 5;
      if (cell < nT) {
        nv = node[(rowB + cell) * 1024 + (cell + i) * 32 + (t & 31)];
        sv = span[(rowB + cell) * 32 + (cell + i)];
      }
    }
    // ---- preamble (in-wave P1): lane (hi,pq) owns cell ct=hi?16+w:w, j=pq ----
    int ct = hi ? 16 + w : w;
    float sc_l = 0.f;
    int rc_l = 0;
    {
      bool on = (ct < nT) && (pq < i);
      float gj = -3.0e38f;
      if (on) {
        int m2 = ct + pq + 1;
        rc_l = m2 * (65 - m2) / 2 + (i - 1 - pq);
        gj = maxv[ct * (65 - ct) / 2 + pq] + maxv[rc_l];
      }
      float gm = gj;
#pragma unroll
      for (int s = 16; s >= 1; s >>= 1) gm = fmaxf(gm, __shfl_xor(gm, s, 32));
      if (ct < nT) {
        sc_l = on ? __expf(gj - gm) : 0.f;
        if (pq == 0) G[ct] = gm;
      }
    }
    // ---- P2: wave w -> cells w and 16+w; S = sum_j (sc*Xl) (x) Xr ----
#pragma unroll 1
    for (int half = 0; half < 2; ++half) {
      int cg = (half << 4) + w;
      if (cg >= nT) break;                 // wave-uniform
      int sb2 = half << 5;                 // shfl source base (other half's lanes)
      const float* xlb = Xt + pq * 529 + cg * (65 - cg) / 2;
      const float* xrr = Xt + pq * 529;
      f32x16 Sacc = {};
#pragma unroll
      for (int kk = 0; kk < 2; ++kk) {
        if (kk == 1 && i <= 16) break;
        int j0 = kk << 4;
        BFU ua, ub;
#pragma unroll
        for (int r2 = 0; r2 < 4; ++r2) {
          int j = j0 + jb + (r2 << 1);
          float s0 = __shfl(sc_l, sb2 + j, 64);
          int c0i = __shfl(rc_l, sb2 + j, 64);
          float s1 = __shfl(sc_l, sb2 + j + 1, 64);
          int c1i = __shfl(rc_l, sb2 + j + 1, 64);
          float a0 = xlb[j] * s0, a1 = xlb[j + 1] * s1;
          ua.u[r2] = (unsigned)hubf(a0) | ((unsigned)hubf(a1) << 16);
          ub.u[r2] = (unsigned)hubf(xrr[c0i]) | ((unsigned)hubf(xrr[c1i]) << 16);
        }
        Sacc = __builtin_amdgcn_mfma_f32_32x32x16_bf16(ua.v, ub.v, Sacc, 0, 0, 0);
      }
      // store S bf16, XOR-swizzled
      char* sbp = Sb + cg * 2052;
#pragma unroll
      for (int rr = 0; rr < 16; ++rr) {
        int p = (rr & 3) + ((rr >> 2) << 3) + (hi << 2);
        int wd = (((p << 4) + (pq >> 1)) ^ (((pq >> 3) & 1) << 4)) ^ (((p >> 2) & 1) << 2);
        *(unsigned short*)(sbp + wd * 4 + ((pq & 1) << 1)) = hubf(Sacc[rr]);
      }
    }
    __syncthreads();   // B1
    // ---- P3: inner = R * S, 32 cells wide, 4-wave k-split; ra loads inline ----
    if (w < 4) {
      f32x16 C0 = {}, C1 = {};
#pragma unroll
      for (int tt = 0; tt < 16; ++tt) {
        int kst = (w << 4) + tt;
        bf16x8 ra = *(const bf16x8*)(Rbf + (kst << 9) + (ln << 3));
        int ko = (kst << 1) + hi;
        int p = ko >> 2, o = ko & 3;
        int wd = (((p << 4) + (o << 2)) ^ ((o & 1) << 4)) ^ (((p >> 2) & 1) << 2);
        const char* sp = Sb + pq * 2052 + wd * 4;
        BFU ub;
        ub.u[0] = *(const unsigned*)sp;
        ub.u[1] = *(const unsigned*)(sp + 4);
        ub.u[2] = *(const unsigned*)(sp + 8);
        ub.u[3] = *(const unsigned*)(sp + 12);
        if (tt & 1) C1 = __builtin_amdgcn_mfma_f32_32x32x16_bf16(ra, ub.v, C1, 0, 0, 0);
        else        C0 = __builtin_amdgcn_mfma_f32_32x32x16_bf16(ra, ub.v, C0, 0, 0, 0);
      }
      // store cell-major (stride 33): value(lane,rr) = (a=arow, cell=pq)
      float* sl = slots + w * 1056;
#pragma unroll
      for (int rr = 0; rr < 16; ++rr) {
        int arow = (rr & 3) + ((rr >> 2) << 3) + (hi << 2);
        sl[pq * 33 + arow] = C0[rr] + C1[rr];
      }
    }
    __syncthreads();   // B2
    // ---- out + renorm fused: thread (cell=t>>5, a=t&31) ----
    {
      int cell = t >> 5, a = t & 31;
      if (cell < nT) {
        int so = cell * 33 + a;
        float pt = slots[so] + slots[1056 + so] + slots[2112 + so] + slots[3168 + so];
        float cnv = G[cell] + __logf(pt) + nv + nv + sv;   // chart + node
        float m = cnv;
#pragma unroll
        for (int s = 16; s >= 1; s >>= 1) m = fmaxf(m, __shfl_xor(m, s, 32));
        int ix = cell * (65 - cell) / 2 + i;
        Xt[a * 529 + ix] = __expf(cnv - m);
        if (a == 0) maxv[ix] = m;
      }
    }
    __syncthreads();   // B3
  }
  // ---- logits ----
  if (t < 32) {
    int len = 0;
#pragma unroll
    for (int l = 0; l < 32; ++l) len += sm[b * 32 + l];
    int e = len - 1;   // cell (0, e) has triangular index e
    float cv = maxv[e] + __logf(Xt[t * 529 + e]) - node[(rowB * 32 + e) * 32 + t];
    out[b * 32 + t] = cv + (rootm[t] - 1.0f) * 1e10f;
  }
}

extern "C" void kernel_launch(void* const* d_in, const int* in_sizes, int n_in,
                              void* d_out, int out_size, void* d_ws, size_t ws_size,
                              hipStream_t stream) {
  const float* ph    = (const float*)d_in[0];
  const float* sh    = (const float*)d_in[1];
  const int*   sm    = (const int*)  d_in[2];
  const float* Wp    = (const float*)d_in[3];
  const float* bp    = (const float*)d_in[4];
  const float* Wn    = (const float*)d_in[5];
  const float* bn    = (const float*)d_in[6];
  const float* Ws    = (const float*)d_in[7];
  const float* bs    = (const float*)d_in[8];
  const float* rs    = (const float*)d_in[9];
  const float* pu    = (const float*)d_in[10];
  const float* rootm = (const float*)d_in[11];
  const float* pm    = (const float*)d_in[12];
  const float* rm    = (const float*)d_in[13];
  const float* pum   = (const float*)d_in[14];
  float* out = (float*)d_out;

  float* ws   = (float*)d_ws;
  float* node = ws + NODE_OFF;
  float* span = ws + SPAN_OFF;
  float* D    = ws + D_OFF;
  unsigned short* Rbf = (unsigned short*)(ws + RBF_OFF);

  hipFuncSetAttribute((const void*)k_chain7,
                      hipFuncAttributeMaxDynamicSharedMemorySize, 152512);
  k_front<<<640, 256, 0, stream>>>(ph, Wn, bn, Ws, bs, sh, Wp, bp, pm, pu, pum,
                                   rs, rm, node, span, D, Rbf);
  k_chain7<<<8, 1024, 152512, stream>>>(node, span, D, Rbf, sm, rootm, out);
}

// Round 13
// 171.465 us; speedup vs baseline: 1.2798x; 1.2798x over previous
//
#include <hip/hip_runtime.h>
#include <math.h>

// B=8, L=32, H=1024, N=32
// ws layout (floats):
#define NODE_OFF   0          // 8192*32
#define CN_OFF     262144     // 8192*32 (diag rows: chart_diag + 2*node)
#define SPAN_OFF   524288     // 8192
#define D_OFF      532480     // 256*32
#define RBF_OFF    540672     // 32768 halfs: frag-order bf16 exp(rules)
#define PART_OFF   557056     // 4*262144
#define PARTS_OFF  1605632    // 4*8192

typedef short bf16x8 __attribute__((ext_vector_type(8)));
typedef float f32x16 __attribute__((ext_vector_type(16)));

union BFU { unsigned u[4]; bf16x8 v; };

__device__ inline short f2bf(float f) {            // RNE f32->bf16
  union { float f; unsigned u; } v; v.f = f;
  unsigned r = (v.u + 0x7FFFu + ((v.u >> 16) & 1u)) >> 16;
  return (short)r;
}

// Fused front kernel, 1408 blocks x 256:
//  0..1023: node split-K GEMM (256 rowgroups x 32 rows x 4 k-slices)
//  1024..1279: posnode + D    1280..1407: Rbf swizzle
__global__ __launch_bounds__(256) void k_pre(
    const float* __restrict__ ph, const float* __restrict__ Wn,
    const float* __restrict__ Ws, const float* __restrict__ sh,
    const float* __restrict__ Wp, const float* __restrict__ bp,
    const float* __restrict__ pmask, const float* __restrict__ pu,
    const float* __restrict__ pum, const float* __restrict__ rs,
    const float* __restrict__ rm, float* __restrict__ part,
    float* __restrict__ partS, float* __restrict__ D,
    unsigned short* __restrict__ Rbf) {
  __shared__ float smem[8448];
  int t = threadIdx.x;
  int bid = blockIdx.x;
  if (bid >= 1280) {  // ---- Rbf: frag-order bf16 of exp(masked rules) ----
    int idx = ((bid - 1280) << 8) + t;       // [kst(64)][lane(64)][r(8)]
    int kst = idx >> 9, ln = (idx >> 3) & 63, r = idx & 7;
    int a = ln & 31;
    int kp = kst * 16 + ((ln >> 5) << 3) + r;   // k' = p*32+q
    float v = __expf(rs[a * 1024 + kp] + (rm[a * 1024 + kp] - 1.0f) * 1e10f);
    Rbf[idx] = (unsigned short)f2bf(v);
    return;
  }
  if (bid >= 1024) {  // ---- posnode + D ----
    float* rowl = smem;
    float* partl = smem + 1024;
    float* posn = smem + 1288;
    int row = bid - 1024;
#pragma unroll
    for (int k = 0; k < 4; ++k) rowl[t + 256 * k] = sh[row * 1024 + t + 256 * k];
    __syncthreads();
    int c = t & 31, seg = t >> 5;
    float pacc = 0.f;
    for (int hh = 0; hh < 128; ++hh)
      pacc += rowl[seg * 128 + hh] * Wp[(seg * 128 + hh) * 32 + c];
    partl[seg * 33 + c] = pacc;
    __syncthreads();
    if (t < 32) {
      float s = 0.f;
#pragma unroll
      for (int k = 0; k < 8; ++k) s += partl[k * 33 + t];
      posn[t] = s + bp[t] + (pmask[t] - 1.0f) * 1e10f;
    }
    __syncthreads();
    if (t < 32) {
      float mq = posn[t];
#pragma unroll
      for (int m = 16; m >= 1; m >>= 1) mq = fmaxf(mq, __shfl_xor(mq, m, 32));
      float sum = 0.f;
#pragma unroll 8
      for (int q = 0; q < 32; ++q)
        sum += __expf(pu[t * 32 + q] + (pum[t * 32 + q] - 1.0f) * 1e15f + posn[q] - mq);
      D[row * 32 + t] = mq + __logf(sum);
    }
    return;
  }
  // ---- node split-K GEMM: 32 rows x 256 K per block ----
  float (*A)[132] = (float(*)[132])smem;            // 32x132
  float (*Wl)[32] = (float(*)[32])(smem + 4224);    // 128x32
  float* Wsl = smem + 8320;                         // 128
  int rg = bid >> 2;
  int s = bid & 3;
  int row0 = rg << 5;
  int h0 = s << 8;
  int r = t >> 3, tc = t & 7, c = tc << 2;
  float acc0 = 0.f, acc1 = 0.f, acc2 = 0.f, acc3 = 0.f, sp = 0.f;
  for (int hc = 0; hc < 2; ++hc) {
    int hb = h0 + (hc << 7);
#pragma unroll
    for (int k = 0; k < 4; ++k) {          // A: 32x128 f32 = 1024 float4
      int f = t + (k << 8);
      int rr = f >> 5, c4 = f & 31;
      *(float4*)&A[rr][c4 << 2] =
          *(const float4*)&ph[(row0 + rr) * 1024 + hb + (c4 << 2)];
    }
#pragma unroll
    for (int k = 0; k < 4; ++k) {          // W: 128x32 f32 = 1024 float4
      int f = t + (k << 8);
      int hh = f >> 3, c4 = f & 7;
      *(float4*)&Wl[hh][c4 << 2] =
          *(const float4*)&Wn[(hb + hh) * 32 + (c4 << 2)];
    }
    if (t < 128) Wsl[t] = Ws[hb + t];
    __syncthreads();
#pragma unroll 2
    for (int h = 0; h < 128; ++h) {
      float a0 = A[r][h];
      float4 wv = *(const float4*)&Wl[h][c];
      acc0 += a0 * wv.x; acc1 += a0 * wv.y; acc2 += a0 * wv.z; acc3 += a0 * wv.w;
      if (tc == 0) sp += a0 * Wsl[h];
    }
    __syncthreads();
  }
  int row = row0 + r;
  float* po = part + s * 262144;
  *(float4*)&po[row * 32 + c] = make_float4(acc0, acc1, acc2, acc3);
  if (tc == 0) partS[s * 8192 + row] = sp;
}

__global__ __launch_bounds__(256) void k_node_reduce(
    const float* __restrict__ part, const float* __restrict__ partS,
    const float* __restrict__ bn, const float* __restrict__ bs,
    const float* __restrict__ D, float* __restrict__ node,
    float* __restrict__ cng, float* __restrict__ span) {
  int t = threadIdx.x;
  int row = blockIdx.x * 8 + (t >> 5);
  int c = t & 31;
  float v = bn[c];
#pragma unroll
  for (int s = 0; s < 4; ++s) v += part[s * 262144 + row * 32 + c];
  node[row * 32 + c] = v;
  int l = (row >> 5) & 31, m = row & 31;
  if (l == m)
    cng[row * 32 + c] = v + D[(row >> 5) * 32 + c] + v;   // chart_diag + node
  if (c == 0) {
    float sp = bs[0];
#pragma unroll
    for (int s = 0; s < 4; ++s) sp += partS[s * 8192 + row];
    span[row] = sp;
  }
}

// One block per batch; chart as NORMALIZED X = exp(cn - rowmax) in LDS
// (transposed [symbol][cellidx], stride 529). Per stage (3 barriers):
// [prefetch + in-wave P1 (T2 via same-wave LDS RAW) + P2] B1 [P3] B2 [out+renorm] B3
// LDS 160704 B:
//   Xt    f32[32*529]   @0
//   Sb    32 x 2052 B   @67712    (bf16 S, XOR-swizzled)
//   slots f32[4*1056]   @133376   (cell-major, stride 33)
//   T2    int2[32][32]  @150272
//   maxv  f32[528]      @158464
//   G     f32[32]       @160576
__global__ __launch_bounds__(1024) void k_chain8(
    const float* __restrict__ node, const float* __restrict__ span,
    const float* __restrict__ cng, const unsigned short* __restrict__ Rbf,
    const int* __restrict__ sm, const float* __restrict__ rootm,
    float* __restrict__ out) {
  extern __shared__ char lds[];
  float* Xt = (float*)lds;
  char* Sb = lds + 67712;
  float* slots = (float*)(lds + 133376);
  int2* T2 = (int2*)(lds + 150272);
  float* maxv = (float*)(lds + 158464);
  float* G = (float*)(lds + 160576);
  const int t = threadIdx.x;
  const int b = blockIdx.x;
  const int w = t >> 6, ln = t & 63;
  const int pq = ln & 31, hi = ln >> 5, jb = hi << 3;
  const int rowB = b * 32;

  // ---- zero-init Xt (NaN-proof) + diagonal init ----
  {
    int l = t >> 5, a = t & 31;
    float dv = cng[((rowB + l) * 32 + l) * 32 + a];   // diag prefetch overlaps
    float* z = (float*)lds;
    for (int idx = t; idx < 16928; idx += 1024) z[idx] = 0.f;
    __syncthreads();
    float m = dv;
#pragma unroll
    for (int s = 16; s >= 1; s >>= 1) m = fmaxf(m, __shfl_xor(m, s, 32));
    int off = l * (65 - l) / 2;
    Xt[a * 529 + off] = __expf(dv - m);
    if (a == 0) maxv[off] = m;
  }
  __syncthreads();

  for (int i = 1; i < 32; ++i) {
    const int nT = 32 - i;
    // ---- out-phase operand prefetch (mapping: cell=t>>5, a=t&31) ----
    float nv = 0.f, sv = 0.f;
    {
      int cell = t >> 5;
      if (cell < nT) {
        nv = node[(rowB + cell) * 1024 + (cell + i) * 32 + (t & 31)];
        sv = span[(rowB + cell) * 32 + (cell + i)];
      }
    }
    // ---- in-wave P1: lane (hi,pq) -> cell ct=hi?16+w:w, j=pq; write T2,G ----
    // Same-wave LDS RAW (write here, read in P2 below) needs no barrier.
    {
      int ct = hi ? 16 + w : w;
      bool on = (ct < nT) && (pq < i);
      float gj = -3.0e38f; int rc = 0;
      if (on) {
        int m2 = ct + pq + 1;
        rc = m2 * (65 - m2) / 2 + (i - 1 - pq);
        gj = maxv[ct * (65 - ct) / 2 + pq] + maxv[rc];
      }
      float gm = gj;
#pragma unroll
      for (int s = 16; s >= 1; s >>= 1) gm = fmaxf(gm, __shfl_xor(gm, s, 32));
      if (ct < nT) {
        float sc = on ? __expf(gj - gm) : 0.f;
        T2[(ct << 5) + pq] = make_int2(__float_as_int(sc), on ? rc : 0);
        if (pq == 0) G[ct] = gm;
      }
    }
    // ---- P2: wave w -> cells w and 16+w; S = sum_j (sc*Xl) (x) Xr ----
#pragma unroll 1
    for (int half = 0; half < 2; ++half) {
      int cg = (half << 4) + w;
      if (cg >= nT) break;                 // wave-uniform
      const float* xlb = Xt + pq * 529 + cg * (65 - cg) / 2;
      const float* xrr = Xt + pq * 529;
      f32x16 Sacc = {};
#pragma unroll
      for (int kk = 0; kk < 2; ++kk) {
        if (kk == 1 && i <= 16) break;
        int j0 = (kk << 4);
        float xl[8], xr[8], sc[8];
#pragma unroll
        for (int r = 0; r < 8; ++r) {
          int2 e = T2[(cg << 5) + j0 + jb + r];
          sc[r] = __int_as_float(e.x);
          xr[r] = xrr[e.y];
          xl[r] = xlb[j0 + jb + r];
        }
        BFU ua, ub;
#pragma unroll
        for (int r2 = 0; r2 < 4; ++r2) {
          unsigned al = (unsigned short)f2bf(sc[2 * r2] * xl[2 * r2]);
          unsigned ah = (unsigned short)f2bf(sc[2 * r2 + 1] * xl[2 * r2 + 1]);
          ua.u[r2] = al | (ah << 16);
          unsigned bl = (unsigned short)f2bf(xr[2 * r2]);
          unsigned bh = (unsigned short)f2bf(xr[2 * r2 + 1]);
          ub.u[r2] = bl | (bh << 16);
        }
        Sacc = __builtin_amdgcn_mfma_f32_32x32x16_bf16(ua.v, ub.v, Sacc, 0, 0, 0);
      }
      // store S bf16, XOR-swizzled
      char* sbp = Sb + cg * 2052;
#pragma unroll
      for (int rr = 0; rr < 16; ++rr) {
        int p = (rr & 3) + ((rr >> 2) << 3) + (hi << 2);
        int wd = (((p << 4) + (pq >> 1)) ^ (((pq >> 3) & 1) << 4)) ^ (((p >> 2) & 1) << 2);
        *(unsigned short*)(sbp + wd * 4 + ((pq & 1) << 1)) = (unsigned short)f2bf(Sacc[rr]);
      }
    }
    __syncthreads();   // B1
    // ---- P3: inner = R * S, 32 cells wide, 4-wave k-split; ra loads inline ----
    if (w < 4) {
      f32x16 C0 = {}, C1 = {};
#pragma unroll
      for (int tt = 0; tt < 16; ++tt) {
        int kst = (w << 4) + tt;
        bf16x8 ra = *(const bf16x8*)(Rbf + (kst << 9) + (ln << 3));
        int ko = (kst << 1) + hi;
        int p = ko >> 2, o = ko & 3;
        int wd = (((p << 4) + (o << 2)) ^ ((o & 1) << 4)) ^ (((p >> 2) & 1) << 2);
        const char* sp = Sb + pq * 2052 + wd * 4;
        BFU ub;
        ub.u[0] = *(const unsigned*)sp;
        ub.u[1] = *(const unsigned*)(sp + 4);
        ub.u[2] = *(const unsigned*)(sp + 8);
        ub.u[3] = *(const unsigned*)(sp + 12);
        if (tt & 1) C1 = __builtin_amdgcn_mfma_f32_32x32x16_bf16(ra, ub.v, C1, 0, 0, 0);
        else        C0 = __builtin_amdgcn_mfma_f32_32x32x16_bf16(ra, ub.v, C0, 0, 0, 0);
      }
      // store cell-major (stride 33): value(lane,rr) = (a=arow, cell=pq)
      float* sl = slots + w * 1056;
#pragma unroll
      for (int rr = 0; rr < 16; ++rr) {
        int arow = (rr & 3) + ((rr >> 2) << 3) + (hi << 2);
        sl[pq * 33 + arow] = C0[rr] + C1[rr];
      }
    }
    __syncthreads();   // B2
    // ---- out + renorm fused: thread (cell=t>>5, a=t&31) ----
    {
      int cell = t >> 5, a = t & 31;
      if (cell < nT) {
        int so = cell * 33 + a;
        float pt = slots[so] + slots[1056 + so] + slots[2112 + so] + slots[3168 + so];
        float cnv = G[cell] + __logf(pt) + nv + nv + sv;   // chart + node
        float m = cnv;
#pragma unroll
        for (int s = 16; s >= 1; s >>= 1) m = fmaxf(m, __shfl_xor(m, s, 32));
        int ix = cell * (65 - cell) / 2 + i;
        Xt[a * 529 + ix] = __expf(cnv - m);
        if (a == 0) maxv[ix] = m;
      }
    }
    __syncthreads();   // B3
  }
  // ---- logits ----
  if (t < 32) {
    int len = 0;
#pragma unroll
    for (int l = 0; l < 32; ++l) len += sm[b * 32 + l];
    int e = len - 1;   // cell (0, e) has triangular index e
    float cv = maxv[e] + __logf(Xt[t * 529 + e]) - node[(rowB * 32 + e) * 32 + t];
    out[b * 32 + t] = cv + (rootm[t] - 1.0f) * 1e10f;
  }
}

extern "C" void kernel_launch(void* const* d_in, const int* in_sizes, int n_in,
                              void* d_out, int out_size, void* d_ws, size_t ws_size,
                              hipStream_t stream) {
  const float* ph    = (const float*)d_in[0];
  const float* sh    = (const float*)d_in[1];
  const int*   sm    = (const int*)  d_in[2];
  const float* Wp    = (const float*)d_in[3];
  const float* bp    = (const float*)d_in[4];
  const float* Wn    = (const float*)d_in[5];
  const float* bn    = (const float*)d_in[6];
  const float* Ws    = (const float*)d_in[7];
  const float* bs    = (const float*)d_in[8];
  const float* rs    = (const float*)d_in[9];
  const float* pu    = (const float*)d_in[10];
  const float* rootm = (const float*)d_in[11];
  const float* pm    = (const float*)d_in[12];
  const float* rm    = (const float*)d_in[13];
  const float* pum   = (const float*)d_in[14];
  float* out = (float*)d_out;

  float* ws    = (float*)d_ws;
  float* node  = ws + NODE_OFF;
  float* cng   = ws + CN_OFF;
  float* span  = ws + SPAN_OFF;
  float* D     = ws + D_OFF;
  unsigned short* Rbf = (unsigned short*)(ws + RBF_OFF);
  float* part  = ws + PART_OFF;
  float* partS = ws + PARTS_OFF;

  hipFuncSetAttribute((const void*)k_chain8,
                      hipFuncAttributeMaxDynamicSharedMemorySize, 160704);
  k_pre<<<1408, 256, 0, stream>>>(ph, Wn, Ws, sh, Wp, bp, pm, pu, pum, rs, rm,
                                  part, partS, D, Rbf);
  k_node_reduce<<<1024, 256, 0, stream>>>(part, partS, bn, bs, D, node, cng, span);
  k_chain8<<<8, 1024, 160704, stream>>>(node, span, cng, Rbf, sm, rootm, out);
}

// Round 15
// 156.342 us; speedup vs baseline: 1.4035x; 1.0967x over previous
//
#include <hip/hip_runtime.h>
#include <math.h>

// B=8, L=32, H=1024, N=32
// ws layout (floats):
#define NODE_OFF   0          // 8192*32
#define SPAN_OFF   262144     // 8192
#define D_OFF      270336     // 256*32
#define RBF_OFF    278528     // 32768 halfs: frag-order bf16 exp(rules)
#define PART_OFF   294912     // 4*262144 split-K node partials
#define PARTS_OFF  1343488    // 4*8192 split-K span partials

typedef short bf16x8 __attribute__((ext_vector_type(8)));
typedef float f32x16 __attribute__((ext_vector_type(16)));

union BFU { unsigned u[4]; bf16x8 v; };

__device__ inline short f2bf(float f) {            // RNE f32->bf16
  union { float f; unsigned u; } v; v.f = f;
  unsigned r = (v.u + 0x7FFFu + ((v.u >> 16) & 1u)) >> 16;
  return (short)r;
}
__device__ __forceinline__ unsigned pk2bf(float lo, float hi) {
  unsigned r;
  asm("v_cvt_pk_bf16_f32 %0, %1, %2" : "=v"(r) : "v"(lo), "v"(hi));
  return r;
}

// Fused front kernel, 1408 blocks x 256:
//  0..1023: node split-K GEMM (256 rowgroups x 32 rows x 4 k-slices)
//  1024..1279: posnode + D    1280..1407: Rbf swizzle
__global__ __launch_bounds__(256) void k_pre(
    const float* __restrict__ ph, const float* __restrict__ Wn,
    const float* __restrict__ Ws, const float* __restrict__ sh,
    const float* __restrict__ Wp, const float* __restrict__ bp,
    const float* __restrict__ pmask, const float* __restrict__ pu,
    const float* __restrict__ pum, const float* __restrict__ rs,
    const float* __restrict__ rm, float* __restrict__ part,
    float* __restrict__ partS, float* __restrict__ D,
    unsigned short* __restrict__ Rbf) {
  __shared__ float smem[8448];
  int t = threadIdx.x;
  int bid = blockIdx.x;
  if (bid >= 1280) {  // ---- Rbf: frag-order bf16 of exp(masked rules) ----
    int idx = ((bid - 1280) << 8) + t;       // [kst(64)][lane(64)][r(8)]
    int kst = idx >> 9, ln = (idx >> 3) & 63, r = idx & 7;
    int a = ln & 31;
    int kp = kst * 16 + ((ln >> 5) << 3) + r;   // k' = p*32+q
    float v = __expf(rs[a * 1024 + kp] + (rm[a * 1024 + kp] - 1.0f) * 1e10f);
    Rbf[idx] = (unsigned short)f2bf(v);
    return;
  }
  if (bid >= 1024) {  // ---- posnode + D ----
    float* rowl = smem;
    float* partl = smem + 1024;
    float* posn = smem + 1288;
    int row = bid - 1024;
#pragma unroll
    for (int k = 0; k < 4; ++k) rowl[t + 256 * k] = sh[row * 1024 + t + 256 * k];
    __syncthreads();
    int c = t & 31, seg = t >> 5;
    float pacc = 0.f;
    for (int hh = 0; hh < 128; ++hh)
      pacc += rowl[seg * 128 + hh] * Wp[(seg * 128 + hh) * 32 + c];
    partl[seg * 33 + c] = pacc;
    __syncthreads();
    if (t < 32) {
      float s = 0.f;
#pragma unroll
      for (int k = 0; k < 8; ++k) s += partl[k * 33 + t];
      posn[t] = s + bp[t] + (pmask[t] - 1.0f) * 1e10f;
    }
    __syncthreads();
    if (t < 32) {
      float mq = posn[t];
#pragma unroll
      for (int m = 16; m >= 1; m >>= 1) mq = fmaxf(mq, __shfl_xor(mq, m, 32));
      float sum = 0.f;
#pragma unroll 8
      for (int q = 0; q < 32; ++q)
        sum += __expf(pu[t * 32 + q] + (pum[t * 32 + q] - 1.0f) * 1e15f + posn[q] - mq);
      D[row * 32 + t] = mq + __logf(sum);
    }
    return;
  }
  // ---- node split-K GEMM: 32 rows x 256 K per block ----
  float (*A)[132] = (float(*)[132])smem;            // 32x132
  float (*Wl)[32] = (float(*)[32])(smem + 4224);    // 128x32
  float* Wsl = smem + 8320;                         // 128
  int rg = bid >> 2;
  int s = bid & 3;
  int row0 = rg << 5;
  int h0 = s << 8;
  int r = t >> 3, tc = t & 7, c = tc << 2;
  float acc0 = 0.f, acc1 = 0.f, acc2 = 0.f, acc3 = 0.f, sp = 0.f;
  for (int hc = 0; hc < 2; ++hc) {
    int hb = h0 + (hc << 7);
#pragma unroll
    for (int k = 0; k < 4; ++k) {          // A: 32x128 f32 = 1024 float4
      int f = t + (k << 8);
      int rr = f >> 5, c4 = f & 31;
      *(float4*)&A[rr][c4 << 2] =
          *(const float4*)&ph[(row0 + rr) * 1024 + hb + (c4 << 2)];
    }
#pragma unroll
    for (int k = 0; k < 4; ++k) {          // W: 128x32 f32 = 1024 float4
      int f = t + (k << 8);
      int hh = f >> 3, c4 = f & 7;
      *(float4*)&Wl[hh][c4 << 2] =
          *(const float4*)&Wn[(hb + hh) * 32 + (c4 << 2)];
    }
    if (t < 128) Wsl[t] = Ws[hb + t];
    __syncthreads();
#pragma unroll 2
    for (int h = 0; h < 128; ++h) {
      float a0 = A[r][h];
      float4 wv = *(const float4*)&Wl[h][c];
      acc0 += a0 * wv.x; acc1 += a0 * wv.y; acc2 += a0 * wv.z; acc3 += a0 * wv.w;
      if (tc == 0) sp += a0 * Wsl[h];
    }
    __syncthreads();
  }
  int row = row0 + r;
  float* po = part + s * 262144;
  *(float4*)&po[row * 32 + c] = make_float4(acc0, acc1, acc2, acc3);
  if (tc == 0) partS[s * 8192 + row] = sp;
}

// One block per batch; entry fuses the split-K reduce (own batch slice).
// Chart as NORMALIZED X = exp(cn - rowmax) in LDS (transposed, stride 529).
// Per stage (3 barriers): [prefetch + in-wave P1 + P2] B1 [P3] B2 [out+renorm] B3
// LDS 160704 B:
//   Xt    f32[32*529]   @0
//   Sb    32 x 2052 B   @67712    (bf16 S, XOR-swizzled)
//   slots f32[4*1056]   @133376   (cell-major, stride 33)
//   T2    int2[32][32]  @150272
//   maxv  f32[528]      @158464
//   G     f32[32]       @160576
__global__ __launch_bounds__(1024) void k_chain9(
    const float* __restrict__ part, const float* __restrict__ partS,
    const float* __restrict__ bn, const float* __restrict__ bs,
    float* __restrict__ node, float* __restrict__ span,
    const float* __restrict__ D, const unsigned short* __restrict__ Rbf,
    const int* __restrict__ sm, const float* __restrict__ rootm,
    float* __restrict__ out) {
  extern __shared__ char lds[];
  float* Xt = (float*)lds;
  char* Sb = lds + 67712;
  float* slots = (float*)(lds + 133376);
  int* T2i = (int*)(lds + 150272);
  float* maxv = (float*)(lds + 158464);
  float* G = (float*)(lds + 160576);
  const int t = threadIdx.x;
  const int b = blockIdx.x;
  const int w = t >> 6, ln = t & 63;
  const int pq = ln & 31, hi = ln >> 5, jb = hi << 3;
  const int rowB = b * 32;

  // ---- entry: fused split-K reduce for this batch (node, span) ----
  {
    int base = b << 15;                      // batch slice: 32768 f32 of node
#pragma unroll
    for (int k = 0; k < 8; ++k) {
      int idx = t + (k << 10);
      float4 v0 = *(const float4*)&part[base + (idx << 2)];
      float4 v1 = *(const float4*)&part[262144 + base + (idx << 2)];
      float4 v2 = *(const float4*)&part[524288 + base + (idx << 2)];
      float4 v3 = *(const float4*)&part[786432 + base + (idx << 2)];
      float4 bb = *(const float4*)&bn[(idx << 2) & 31];
      *(float4*)&node[base + (idx << 2)] =
          make_float4(v0.x + v1.x + v2.x + v3.x + bb.x,
                      v0.y + v1.y + v2.y + v3.y + bb.y,
                      v0.z + v1.z + v2.z + v3.z + bb.z,
                      v0.w + v1.w + v2.w + v3.w + bb.w);
    }
    int row = (b << 10) + t;
    span[row] = bs[0] + partS[row] + partS[8192 + row] +
                partS[16384 + row] + partS[24576 + row];
    // zero-init Xt region (NaN-proof)
    float* z = (float*)lds;
    for (int idx = t; idx < 16928; idx += 1024) z[idx] = 0.f;
  }
  __syncthreads();
  // ---- diagonal init from node & D ----
  {
    int l = t >> 5, a = t & 31;
    float nd = node[(b << 15) + (l << 10) + (l << 5) + a];
    float dv = nd + nd + D[(rowB + l) * 32 + a];
    float m = dv;
#pragma unroll
    for (int s = 16; s >= 1; s >>= 1) m = fmaxf(m, __shfl_xor(m, s, 32));
    int off = l * (65 - l) / 2;
    Xt[a * 529 + off] = __expf(dv - m);
    if (a == 0) maxv[off] = m;
  }
  __syncthreads();

  for (int i = 1; i < 32; ++i) {
    const int nT = 32 - i;
    // ---- out-phase operand prefetch (mapping: cell=t>>5, a=t&31) ----
    float nv = 0.f, sv = 0.f;
    {
      int cell = t >> 5;
      if (cell < nT) {
        nv = node[(rowB + cell) * 1024 + (cell + i) * 32 + (t & 31)];
        sv = span[(rowB + cell) * 32 + (cell + i)];
      }
    }
    // ---- in-wave P1: lane (hi,pq) -> cell ct=hi?16+w:w, j=pq; write T2,G ----
    {
      int ct = hi ? 16 + w : w;
      bool on = (ct < nT) && (pq < i);
      float gj = -3.0e38f; int rc = 0;
      if (on) {
        int m2 = ct + pq + 1;
        rc = m2 * (65 - m2) / 2 + (i - 1 - pq);
        gj = maxv[ct * (65 - ct) / 2 + pq] + maxv[rc];
      }
      float gm = gj;
#pragma unroll
      for (int s = 16; s >= 1; s >>= 1) gm = fmaxf(gm, __shfl_xor(gm, s, 32));
      if (ct < nT) {
        float sc = on ? __expf(gj - gm) : 0.f;
        T2i[(ct << 6) + (pq << 1)] = __float_as_int(sc);
        T2i[(ct << 6) + (pq << 1) + 1] = on ? rc : 0;
        if (pq == 0) G[ct] = gm;
      }
    }
    // ---- P2: wave w -> cells w and 16+w; S = sum_j (sc*Xl) (x) Xr ----
#pragma unroll 1
    for (int half = 0; half < 2; ++half) {
      int cg = (half << 4) + w;
      if (cg >= nT) break;                 // wave-uniform
      const float* xlb = Xt + pq * 529 + cg * (65 - cg) / 2;
      const float* xrr = Xt + pq * 529;
      f32x16 Sacc = {};
#pragma unroll
      for (int kk = 0; kk < 2; ++kk) {
        if (kk == 1 && i <= 16) break;
        int j0 = (kk << 4);
        const int4* t4 = (const int4*)(T2i + (cg << 6) + ((j0 + jb) << 1));
        BFU ua, ub;
#pragma unroll
        for (int r2 = 0; r2 < 4; ++r2) {
          int4 e = t4[r2];                 // {sc0, rc0, sc1, rc1} broadcast
          int j = j0 + jb + (r2 << 1);
          float a0 = xlb[j] * __int_as_float(e.x);
          float a1 = xlb[j + 1] * __int_as_float(e.z);
          ua.u[r2] = pk2bf(a0, a1);
          ub.u[r2] = pk2bf(xrr[e.y], xrr[e.w]);
        }
        Sacc = __builtin_amdgcn_mfma_f32_32x32x16_bf16(ua.v, ub.v, Sacc, 0, 0, 0);
      }
      // store S bf16 (pk-pairs), XOR-swizzled layout identical to chain8.
      // p0 even => bit4 of pre-XOR word index is 0 => (p0+1) variant is wd0^16.
      char* sbp = Sb + cg * 2052;
#pragma unroll
      for (int rr = 0; rr < 16; rr += 2) {
        unsigned pk = pk2bf(Sacc[rr], Sacc[rr + 1]);
        int p0 = (rr & 3) + ((rr >> 2) << 3) + (hi << 2);   // p for rr; rr+1 -> p0+1
        int sw = (((pq >> 3) & 1) << 4) ^ (((p0 >> 2) & 1) << 2);  // same for p0,p0+1
        int wd0 = (((p0 << 4) + (pq >> 1)) ^ sw);
        int wd1 = wd0 ^ 16;                                  // XOR, not add (bit4=0 pre-XOR)
        *(unsigned short*)(sbp + wd0 * 4 + ((pq & 1) << 1)) = (unsigned short)pk;
        *(unsigned short*)(sbp + wd1 * 4 + ((pq & 1) << 1)) = (unsigned short)(pk >> 16);
      }
    }
    __syncthreads();   // B1
    // ---- P3: inner = R * S, 32 cells wide, 4-wave k-split; ra loads inline ----
    if (w < 4) {
      f32x16 C0 = {}, C1 = {};
#pragma unroll
      for (int tt = 0; tt < 16; ++tt) {
        int kst = (w << 4) + tt;
        bf16x8 ra = *(const bf16x8*)(Rbf + (kst << 9) + (ln << 3));
        int ko = (kst << 1) + hi;
        int p = ko >> 2, o = ko & 3;
        int wd = (((p << 4) + (o << 2)) ^ ((o & 1) << 4)) ^ (((p >> 2) & 1) << 2);
        const char* sp = Sb + pq * 2052 + wd * 4;
        BFU ub;
        ub.u[0] = *(const unsigned*)sp;
        ub.u[1] = *(const unsigned*)(sp + 4);
        ub.u[2] = *(const unsigned*)(sp + 8);
        ub.u[3] = *(const unsigned*)(sp + 12);
        if (tt & 1) C1 = __builtin_amdgcn_mfma_f32_32x32x16_bf16(ra, ub.v, C1, 0, 0, 0);
        else        C0 = __builtin_amdgcn_mfma_f32_32x32x16_bf16(ra, ub.v, C0, 0, 0, 0);
      }
      // store cell-major (stride 33): value(lane,rr) = (a=arow, cell=pq)
      float* sl = slots + w * 1056;
#pragma unroll
      for (int rr = 0; rr < 16; ++rr) {
        int arow = (rr & 3) + ((rr >> 2) << 3) + (hi << 2);
        sl[pq * 33 + arow] = C0[rr] + C1[rr];
      }
    }
    __syncthreads();   // B2
    // ---- out + renorm fused: thread (cell=t>>5, a=t&31) ----
    {
      int cell = t >> 5, a = t & 31;
      if (cell < nT) {
        int so = cell * 33 + a;
        float pt = slots[so] + slots[1056 + so] + slots[2112 + so] + slots[3168 + so];
        float cnv = G[cell] + __logf(pt) + nv + nv + sv;   // chart + node
        float m = cnv;
#pragma unroll
        for (int s = 16; s >= 1; s >>= 1) m = fmaxf(m, __shfl_xor(m, s, 32));
        int ix = cell * (65 - cell) / 2 + i;
        Xt[a * 529 + ix] = __expf(cnv - m);
        if (a == 0) maxv[ix] = m;
      }
    }
    __syncthreads();   // B3
  }
  // ---- logits ----
  if (t < 32) {
    int len = 0;
#pragma unroll
    for (int l = 0; l < 32; ++l) len += sm[b * 32 + l];
    int e = len - 1;   // cell (0, e) has triangular index e
    float cv = maxv[e] + __logf(Xt[t * 529 + e]) - node[(rowB * 32 + e) * 32 + t];
    out[b * 32 + t] = cv + (rootm[t] - 1.0f) * 1e10f;
  }
}

extern "C" void kernel_launch(void* const* d_in, const int* in_sizes, int n_in,
                              void* d_out, int out_size, void* d_ws, size_t ws_size,
                              hipStream_t stream) {
  const float* ph    = (const float*)d_in[0];
  const float* sh    = (const float*)d_in[1];
  const int*   sm    = (const int*)  d_in[2];
  const float* Wp    = (const float*)d_in[3];
  const float* bp    = (const float*)d_in[4];
  const float* Wn    = (const float*)d_in[5];
  const float* bn    = (const float*)d_in[6];
  const float* Ws    = (const float*)d_in[7];
  const float* bs    = (const float*)d_in[8];
  const float* rs    = (const float*)d_in[9];
  const float* pu    = (const float*)d_in[10];
  const float* rootm = (const float*)d_in[11];
  const float* pm    = (const float*)d_in[12];
  const float* rm    = (const float*)d_in[13];
  const float* pum   = (const float*)d_in[14];
  float* out = (float*)d_out;

  float* ws    = (float*)d_ws;
  float* node  = ws + NODE_OFF;
  float* span  = ws + SPAN_OFF;
  float* D     = ws + D_OFF;
  unsigned short* Rbf = (unsigned short*)(ws + RBF_OFF);
  float* part  = ws + PART_OFF;
  float* partS = ws + PARTS_OFF;

  hipFuncSetAttribute((const void*)k_chain9,
                      hipFuncAttributeMaxDynamicSharedMemorySize, 160704);
  k_pre<<<1408, 256, 0, stream>>>(ph, Wn, Ws, sh, Wp, bp, pm, pu, pum, rs, rm,
                                  part, partS, D, Rbf);
  k_chain9<<<8, 1024, 160704, stream>>>(part, partS, bn, bs, node, span, D, Rbf,
                                        sm, rootm, out);
}

// Round 16
// 141.692 us; speedup vs baseline: 1.5487x; 1.1034x over previous
//
#include <hip/hip_runtime.h>
#include <math.h>

// B=8, L=32, H=1024, N=32
// ws layout (floats):
#define NODE_OFF   0          // 8192*32
#define SPAN_OFF   262144     // 8192
#define D_OFF      270336     // 256*32
#define RBF_OFF    278528     // 32768 halfs: frag-order bf16 exp(rules)
#define PART_OFF   294912     // 4*262144 split-K node partials
#define PARTS_OFF  1343488    // 4*8192 split-K span partials

typedef short bf16x8 __attribute__((ext_vector_type(8)));
typedef float f32x16 __attribute__((ext_vector_type(16)));

union BFU { unsigned u[4]; bf16x8 v; };

__device__ inline short f2bf(float f) {            // RNE f32->bf16
  union { float f; unsigned u; } v; v.f = f;
  unsigned r = (v.u + 0x7FFFu + ((v.u >> 16) & 1u)) >> 16;
  return (short)r;
}
__device__ __forceinline__ unsigned short hubf(float f) {  // half-up round
  return (unsigned short)((__float_as_uint(f) + 0x8000u) >> 16);
}
__device__ __forceinline__ float bfup(unsigned short u) {
  return __uint_as_float(((unsigned)u) << 16);
}
__device__ __forceinline__ unsigned pk2bf(float lo, float hi) {
  unsigned r;
  asm("v_cvt_pk_bf16_f32 %0, %1, %2" : "=v"(r) : "v"(lo), "v"(hi));
  return r;
}

// Fused front kernel, 1408 blocks x 256:
//  0..1023: node split-K GEMM via MFMA (256 rowgroups x 32 rows x 4 k-slices)
//  1024..1279: posnode + D    1280..1407: Rbf swizzle
__global__ __launch_bounds__(256) void k_pre(
    const float* __restrict__ ph, const float* __restrict__ Wn,
    const float* __restrict__ Ws, const float* __restrict__ sh,
    const float* __restrict__ Wp, const float* __restrict__ bp,
    const float* __restrict__ pmask, const float* __restrict__ pu,
    const float* __restrict__ pum, const float* __restrict__ rs,
    const float* __restrict__ rm, float* __restrict__ part,
    float* __restrict__ partS, float* __restrict__ D,
    unsigned short* __restrict__ Rbf) {
  __shared__ float smem[8704];   // 34,816 B
  int t = threadIdx.x;
  int bid = blockIdx.x;
  if (bid >= 1280) {  // ---- Rbf: frag-order bf16 of exp(masked rules) ----
    int idx = ((bid - 1280) << 8) + t;       // [kst(64)][lane(64)][r(8)]
    int kst = idx >> 9, ln = (idx >> 3) & 63, r = idx & 7;
    int a = ln & 31;
    int kp = kst * 16 + ((ln >> 5) << 3) + r;   // k' = p*32+q
    float v = __expf(rs[a * 1024 + kp] + (rm[a * 1024 + kp] - 1.0f) * 1e10f);
    Rbf[idx] = (unsigned short)f2bf(v);
    return;
  }
  if (bid >= 1024) {  // ---- posnode + D ----
    float* rowl = smem;
    float* partl = smem + 1024;
    float* posn = smem + 1288;
    int row = bid - 1024;
#pragma unroll
    for (int k = 0; k < 4; ++k) rowl[t + 256 * k] = sh[row * 1024 + t + 256 * k];
    __syncthreads();
    int c = t & 31, seg = t >> 5;
    float pacc = 0.f;
    for (int hh = 0; hh < 128; ++hh)
      pacc += rowl[seg * 128 + hh] * Wp[(seg * 128 + hh) * 32 + c];
    partl[seg * 33 + c] = pacc;
    __syncthreads();
    if (t < 32) {
      float s = 0.f;
#pragma unroll
      for (int k = 0; k < 8; ++k) s += partl[k * 33 + t];
      posn[t] = s + bp[t] + (pmask[t] - 1.0f) * 1e10f;
    }
    __syncthreads();
    if (t < 32) {
      float mq = posn[t];
#pragma unroll
      for (int m = 16; m >= 1; m >>= 1) mq = fmaxf(mq, __shfl_xor(mq, m, 32));
      float sum = 0.f;
#pragma unroll 8
      for (int q = 0; q < 32; ++q)
        sum += __expf(pu[t * 32 + q] + (pum[t * 32 + q] - 1.0f) * 1e15f + posn[q] - mq);
      D[row * 32 + t] = mq + __logf(sum);
    }
    return;
  }
  // ---- node split-K GEMM via MFMA: 32 rows x 256 K per block ----
  // LDS: As bf16[32][264] @word0, Wt bf16[32][264] @word4224, Wsl f32 @8448
  // slots f32[4096] aliases As (after frag/span reads complete).
  unsigned short* As = (unsigned short*)smem;
  unsigned short* Wt = ((unsigned short*)smem) + 8448;
  float* Wsl = smem + 8448;
  float* slots = smem;
  int rg = bid >> 2, s = bid & 3;
  int row0 = rg << 5, k0 = s << 8;
  // stage A: 32x256 f32 -> bf16 (coalesced float4 reads, u32 LDS writes)
#pragma unroll
  for (int u = 0; u < 8; ++u) {
    int idx = t + (u << 8);            // 0..2047
    int r = idx >> 6, f4 = idx & 63;
    float4 v = *(const float4*)&ph[(row0 + r) * 1024 + k0 + (f4 << 2)];
    unsigned* dst = (unsigned*)(As + r * 264 + (f4 << 2));
    dst[0] = pk2bf(v.x, v.y);
    dst[1] = pk2bf(v.z, v.w);
  }
  // stage Wt: transpose Wn[k0..k0+256][32] -> Wt[c][k] bf16
#pragma unroll
  for (int u = 0; u < 8; ++u) {
    int idx = t + (u << 8);            // 0..2047
    int k = idx >> 3, c4 = idx & 7;
    float4 v = *(const float4*)&Wn[(k0 + k) * 32 + (c4 << 2)];
    int cb = c4 << 2;
    Wt[(cb + 0) * 264 + k] = hubf(v.x);
    Wt[(cb + 1) * 264 + k] = hubf(v.y);
    Wt[(cb + 2) * 264 + k] = hubf(v.z);
    Wt[(cb + 3) * 264 + k] = hubf(v.w);
  }
  if (t < 256) Wsl[t] = Ws[k0 + t];
  __syncthreads();
  // MFMA: wave wv owns k-window [wv*64, wv*64+64) of this block's 256
  int wv = t >> 6, ln2 = t & 63;
  int m31 = ln2 & 31, hi2 = ln2 >> 5;
  f32x16 C = {};
#pragma unroll
  for (int kc = 0; kc < 64; kc += 16) {
    int ko = (wv << 6) + kc + (hi2 << 3);
    bf16x8 af = *(const bf16x8*)(As + m31 * 264 + ko);
    bf16x8 bfv = *(const bf16x8*)(Wt + m31 * 264 + ko);
    C = __builtin_amdgcn_mfma_f32_32x32x16_bf16(af, bfv, C, 0, 0, 0);
  }
  // span partial (bf16 dot, lanes 0..31 of wave 0), before As is overwritten
  float spn = 0.f;
  if (t < 32) {
#pragma unroll 4
    for (int kk = 0; kk < 256; kk += 8) {
      bf16x8 avv = *(const bf16x8*)(As + t * 264 + kk);
#pragma unroll
      for (int e = 0; e < 8; ++e)
        spn += bfup((unsigned short)avv[e]) * Wsl[kk + e];
    }
  }
  __syncthreads();   // all As/Wt reads complete
  // write C to slots (alias As region)
  float* sl = slots + (wv << 10);
#pragma unroll
  for (int rr = 0; rr < 16; ++rr) {
    int arow = (rr & 3) + ((rr >> 2) << 3) + (hi2 << 2);
    sl[arow * 32 + m31] = C[rr];
  }
  __syncthreads();
  // in-block 4-way k-reduce -> part slice s
#pragma unroll
  for (int u = 0; u < 4; ++u) {
    int idx = t + (u << 8);            // 0..1023 = r*32+c
    part[s * 262144 + (row0 << 5) + idx] =
        slots[idx] + slots[1024 + idx] + slots[2048 + idx] + slots[3072 + idx];
  }
  if (t < 32) partS[s * 8192 + row0 + t] = spn;
}

// One block per batch; entry fuses the split-K reduce (own batch slice).
// Chart as NORMALIZED X = exp(cn - rowmax) in LDS (transposed, stride 529).
// Per stage (3 barriers): [prefetch + in-wave P1 + P2] B1 [P3] B2 [out+renorm] B3
// LDS 160704 B (layout as R15).
__global__ __launch_bounds__(1024) void k_chain9(
    const float* __restrict__ part, const float* __restrict__ partS,
    const float* __restrict__ bn, const float* __restrict__ bs,
    float* __restrict__ node, float* __restrict__ span,
    const float* __restrict__ D, const unsigned short* __restrict__ Rbf,
    const int* __restrict__ sm, const float* __restrict__ rootm,
    float* __restrict__ out) {
  extern __shared__ char lds[];
  float* Xt = (float*)lds;
  char* Sb = lds + 67712;
  float* slots = (float*)(lds + 133376);
  int* T2i = (int*)(lds + 150272);
  float* maxv = (float*)(lds + 158464);
  float* G = (float*)(lds + 160576);
  const int t = threadIdx.x;
  const int b = blockIdx.x;
  const int w = t >> 6, ln = t & 63;
  const int pq = ln & 31, hi = ln >> 5, jb = hi << 3;
  const int rowB = b * 32;

  // ---- entry: fused split-K reduce for this batch (node, span) ----
  {
    int base = b << 15;
#pragma unroll
    for (int k = 0; k < 8; ++k) {
      int idx = t + (k << 10);
      float4 v0 = *(const float4*)&part[base + (idx << 2)];
      float4 v1 = *(const float4*)&part[262144 + base + (idx << 2)];
      float4 v2 = *(const float4*)&part[524288 + base + (idx << 2)];
      float4 v3 = *(const float4*)&part[786432 + base + (idx << 2)];
      float4 bb = *(const float4*)&bn[(idx << 2) & 31];
      *(float4*)&node[base + (idx << 2)] =
          make_float4(v0.x + v1.x + v2.x + v3.x + bb.x,
                      v0.y + v1.y + v2.y + v3.y + bb.y,
                      v0.z + v1.z + v2.z + v3.z + bb.z,
                      v0.w + v1.w + v2.w + v3.w + bb.w);
    }
    int row = (b << 10) + t;
    span[row] = bs[0] + partS[row] + partS[8192 + row] +
                partS[16384 + row] + partS[24576 + row];
    float* z = (float*)lds;
    for (int idx = t; idx < 16928; idx += 1024) z[idx] = 0.f;
  }
  __syncthreads();
  // ---- diagonal init from node & D ----
  {
    int l = t >> 5, a = t & 31;
    float nd = node[(b << 15) + (l << 10) + (l << 5) + a];
    float dv = nd + nd + D[(rowB + l) * 32 + a];
    float m = dv;
#pragma unroll
    for (int s = 16; s >= 1; s >>= 1) m = fmaxf(m, __shfl_xor(m, s, 32));
    int off = l * (65 - l) / 2;
    Xt[a * 529 + off] = __expf(dv - m);
    if (a == 0) maxv[off] = m;
  }
  __syncthreads();

  for (int i = 1; i < 32; ++i) {
    const int nT = 32 - i;
    float nv = 0.f, sv = 0.f;
    {
      int cell = t >> 5;
      if (cell < nT) {
        nv = node[(rowB + cell) * 1024 + (cell + i) * 32 + (t & 31)];
        sv = span[(rowB + cell) * 32 + (cell + i)];
      }
    }
    // ---- in-wave P1 ----
    {
      int ct = hi ? 16 + w : w;
      bool on = (ct < nT) && (pq < i);
      float gj = -3.0e38f; int rc = 0;
      if (on) {
        int m2 = ct + pq + 1;
        rc = m2 * (65 - m2) / 2 + (i - 1 - pq);
        gj = maxv[ct * (65 - ct) / 2 + pq] + maxv[rc];
      }
      float gm = gj;
#pragma unroll
      for (int s = 16; s >= 1; s >>= 1) gm = fmaxf(gm, __shfl_xor(gm, s, 32));
      if (ct < nT) {
        float sc = on ? __expf(gj - gm) : 0.f;
        T2i[(ct << 6) + (pq << 1)] = __float_as_int(sc);
        T2i[(ct << 6) + (pq << 1) + 1] = on ? rc : 0;
        if (pq == 0) G[ct] = gm;
      }
    }
    // ---- P2 ----
#pragma unroll 1
    for (int half = 0; half < 2; ++half) {
      int cg = (half << 4) + w;
      if (cg >= nT) break;
      const float* xlb = Xt + pq * 529 + cg * (65 - cg) / 2;
      const float* xrr = Xt + pq * 529;
      f32x16 Sacc = {};
#pragma unroll
      for (int kk = 0; kk < 2; ++kk) {
        if (kk == 1 && i <= 16) break;
        int j0 = (kk << 4);
        const int4* t4 = (const int4*)(T2i + (cg << 6) + ((j0 + jb) << 1));
        BFU ua, ub;
#pragma unroll
        for (int r2 = 0; r2 < 4; ++r2) {
          int4 e = t4[r2];
          int j = j0 + jb + (r2 << 1);
          float a0 = xlb[j] * __int_as_float(e.x);
          float a1 = xlb[j + 1] * __int_as_float(e.z);
          ua.u[r2] = pk2bf(a0, a1);
          ub.u[r2] = pk2bf(xrr[e.y], xrr[e.w]);
        }
        Sacc = __builtin_amdgcn_mfma_f32_32x32x16_bf16(ua.v, ub.v, Sacc, 0, 0, 0);
      }
      char* sbp = Sb + cg * 2052;
#pragma unroll
      for (int rr = 0; rr < 16; rr += 2) {
        unsigned pk = pk2bf(Sacc[rr], Sacc[rr + 1]);
        int p0 = (rr & 3) + ((rr >> 2) << 3) + (hi << 2);
        int sw = (((pq >> 3) & 1) << 4) ^ (((p0 >> 2) & 1) << 2);
        int wd0 = (((p0 << 4) + (pq >> 1)) ^ sw);
        int wd1 = wd0 ^ 16;
        *(unsigned short*)(sbp + wd0 * 4 + ((pq & 1) << 1)) = (unsigned short)pk;
        *(unsigned short*)(sbp + wd1 * 4 + ((pq & 1) << 1)) = (unsigned short)(pk >> 16);
      }
    }
    __syncthreads();   // B1
    // ---- P3 ----
    if (w < 4) {
      f32x16 C0 = {}, C1 = {};
#pragma unroll
      for (int tt = 0; tt < 16; ++tt) {
        int kst = (w << 4) + tt;
        bf16x8 ra = *(const bf16x8*)(Rbf + (kst << 9) + (ln << 3));
        int ko = (kst << 1) + hi;
        int p = ko >> 2, o = ko & 3;
        int wd = (((p << 4) + (o << 2)) ^ ((o & 1) << 4)) ^ (((p >> 2) & 1) << 2);
        const char* sp = Sb + pq * 2052 + wd * 4;
        BFU ub;
        ub.u[0] = *(const unsigned*)sp;
        ub.u[1] = *(const unsigned*)(sp + 4);
        ub.u[2] = *(const unsigned*)(sp + 8);
        ub.u[3] = *(const unsigned*)(sp + 12);
        if (tt & 1) C1 = __builtin_amdgcn_mfma_f32_32x32x16_bf16(ra, ub.v, C1, 0, 0, 0);
        else        C0 = __builtin_amdgcn_mfma_f32_32x32x16_bf16(ra, ub.v, C0, 0, 0, 0);
      }
      float* sl = slots + w * 1056;
#pragma unroll
      for (int rr = 0; rr < 16; ++rr) {
        int arow = (rr & 3) + ((rr >> 2) << 3) + (hi << 2);
        sl[pq * 33 + arow] = C0[rr] + C1[rr];
      }
    }
    __syncthreads();   // B2
    // ---- out + renorm fused ----
    {
      int cell = t >> 5, a = t & 31;
      if (cell < nT) {
        int so = cell * 33 + a;
        float pt = slots[so] + slots[1056 + so] + slots[2112 + so] + slots[3168 + so];
        float cnv = G[cell] + __logf(pt) + nv + nv + sv;
        float m = cnv;
#pragma unroll
        for (int s = 16; s >= 1; s >>= 1) m = fmaxf(m, __shfl_xor(m, s, 32));
        int ix = cell * (65 - cell) / 2 + i;
        Xt[a * 529 + ix] = __expf(cnv - m);
        if (a == 0) maxv[ix] = m;
      }
    }
    __syncthreads();   // B3
  }
  // ---- logits ----
  if (t < 32) {
    int len = 0;
#pragma unroll
    for (int l = 0; l < 32; ++l) len += sm[b * 32 + l];
    int e = len - 1;
    float cv = maxv[e] + __logf(Xt[t * 529 + e]) - node[(rowB * 32 + e) * 32 + t];
    out[b * 32 + t] = cv + (rootm[t] - 1.0f) * 1e10f;
  }
}

extern "C" void kernel_launch(void* const* d_in, const int* in_sizes, int n_in,
                              void* d_out, int out_size, void* d_ws, size_t ws_size,
                              hipStream_t stream) {
  const float* ph    = (const float*)d_in[0];
  const float* sh    = (const float*)d_in[1];
  const int*   sm    = (const int*)  d_in[2];
  const float* Wp    = (const float*)d_in[3];
  const float* bp    = (const float*)d_in[4];
  const float* Wn    = (const float*)d_in[5];
  const float* bn    = (const float*)d_in[6];
  const float* Ws    = (const float*)d_in[7];
  const float* bs    = (const float*)d_in[8];
  const float* rs    = (const float*)d_in[9];
  const float* pu    = (const float*)d_in[10];
  const float* rootm = (const float*)d_in[11];
  const float* pm    = (const float*)d_in[12];
  const float* rm    = (const float*)d_in[13];
  const float* pum   = (const float*)d_in[14];
  float* out = (float*)d_out;

  float* ws    = (float*)d_ws;
  float* node  = ws + NODE_OFF;
  float* span  = ws + SPAN_OFF;
  float* D     = ws + D_OFF;
  unsigned short* Rbf = (unsigned short*)(ws + RBF_OFF);
  float* part  = ws + PART_OFF;
  float* partS = ws + PARTS_OFF;

  hipFuncSetAttribute((const void*)k_chain9,
                      hipFuncAttributeMaxDynamicSharedMemorySize, 160704);
  k_pre<<<1408, 256, 0, stream>>>(ph, Wn, Ws, sh, Wp, bp, pm, pu, pum, rs, rm,
                                  part, partS, D, Rbf);
  k_chain9<<<8, 1024, 160704, stream>>>(part, partS, bn, bs, node, span, D, Rbf,
                                        sm, rootm, out);
}

// Round 17
// 133.440 us; speedup vs baseline: 1.6444x; 1.0618x over previous
//
#include <hip/hip_runtime.h>
#include <math.h>

// B=8, L=32, H=1024, N=32
// ws layout (floats):
#define NODE_OFF   0          // 8192*32
#define SPAN_OFF   262144     // 8192
#define D_OFF      270336     // 256*32
#define RBF_OFF    278528     // 32768 halfs: frag-order bf16 exp(rules)
#define PART_OFF   294912     // 4*262144 split-K node partials
#define PARTS_OFF  1343488    // 4*8192 split-K span partials

typedef short bf16x8 __attribute__((ext_vector_type(8)));
typedef float f32x16 __attribute__((ext_vector_type(16)));

union BFU { unsigned u[4]; bf16x8 v; };

__device__ inline short f2bf(float f) {            // RNE f32->bf16
  union { float f; unsigned u; } v; v.f = f;
  unsigned r = (v.u + 0x7FFFu + ((v.u >> 16) & 1u)) >> 16;
  return (short)r;
}
__device__ __forceinline__ unsigned short hubf(float f) {  // half-up round
  return (unsigned short)((__float_as_uint(f) + 0x8000u) >> 16);
}
__device__ __forceinline__ float bfup(unsigned short u) {
  return __uint_as_float(((unsigned)u) << 16);
}
__device__ __forceinline__ unsigned pk2bf(float lo, float hi) {
  unsigned r;
  asm("v_cvt_pk_bf16_f32 %0, %1, %2" : "=v"(r) : "v"(lo), "v"(hi));
  return r;
}

// Fused front kernel, 1408 blocks x 256:
//  0..1023: node split-K GEMM via MFMA (256 rowgroups x 32 rows x 4 k-slices)
//  1024..1279: posnode + D    1280..1407: Rbf swizzle
__global__ __launch_bounds__(256) void k_pre(
    const float* __restrict__ ph, const float* __restrict__ Wn,
    const float* __restrict__ Ws, const float* __restrict__ sh,
    const float* __restrict__ Wp, const float* __restrict__ bp,
    const float* __restrict__ pmask, const float* __restrict__ pu,
    const float* __restrict__ pum, const float* __restrict__ rs,
    const float* __restrict__ rm, float* __restrict__ part,
    float* __restrict__ partS, float* __restrict__ D,
    unsigned short* __restrict__ Rbf) {
  __shared__ float smem[8704];   // 34,816 B
  int t = threadIdx.x;
  int bid = blockIdx.x;
  if (bid >= 1280) {  // ---- Rbf: frag-order bf16 of exp(masked rules) ----
    int idx = ((bid - 1280) << 8) + t;       // [kst(64)][lane(64)][r(8)]
    int kst = idx >> 9, ln = (idx >> 3) & 63, r = idx & 7;
    int a = ln & 31;
    int kp = kst * 16 + ((ln >> 5) << 3) + r;   // k' = p*32+q
    float v = __expf(rs[a * 1024 + kp] + (rm[a * 1024 + kp] - 1.0f) * 1e10f);
    Rbf[idx] = (unsigned short)f2bf(v);
    return;
  }
  if (bid >= 1024) {  // ---- posnode + D ----
    float* rowl = smem;
    float* partl = smem + 1024;
    float* posn = smem + 1288;
    int row = bid - 1024;
#pragma unroll
    for (int k = 0; k < 4; ++k) rowl[t + 256 * k] = sh[row * 1024 + t + 256 * k];
    __syncthreads();
    int c = t & 31, seg = t >> 5;
    float pacc = 0.f;
    for (int hh = 0; hh < 128; ++hh)
      pacc += rowl[seg * 128 + hh] * Wp[(seg * 128 + hh) * 32 + c];
    partl[seg * 33 + c] = pacc;
    __syncthreads();
    if (t < 32) {
      float s = 0.f;
#pragma unroll
      for (int k = 0; k < 8; ++k) s += partl[k * 33 + t];
      posn[t] = s + bp[t] + (pmask[t] - 1.0f) * 1e10f;
    }
    __syncthreads();
    if (t < 32) {
      float mq = posn[t];
#pragma unroll
      for (int m = 16; m >= 1; m >>= 1) mq = fmaxf(mq, __shfl_xor(mq, m, 32));
      float sum = 0.f;
#pragma unroll 8
      for (int q = 0; q < 32; ++q)
        sum += __expf(pu[t * 32 + q] + (pum[t * 32 + q] - 1.0f) * 1e15f + posn[q] - mq);
      D[row * 32 + t] = mq + __logf(sum);
    }
    return;
  }
  // ---- node split-K GEMM via MFMA: 32 rows x 256 K per block ----
  unsigned short* As = (unsigned short*)smem;
  unsigned short* Wt = ((unsigned short*)smem) + 8448;
  float* Wsl = smem + 8448;
  float* slots = smem;
  int rg = bid >> 2, s = bid & 3;
  int row0 = rg << 5, k0 = s << 8;
#pragma unroll
  for (int u = 0; u < 8; ++u) {
    int idx = t + (u << 8);
    int r = idx >> 6, f4 = idx & 63;
    float4 v = *(const float4*)&ph[(row0 + r) * 1024 + k0 + (f4 << 2)];
    unsigned* dst = (unsigned*)(As + r * 264 + (f4 << 2));
    dst[0] = pk2bf(v.x, v.y);
    dst[1] = pk2bf(v.z, v.w);
  }
#pragma unroll
  for (int u = 0; u < 8; ++u) {
    int idx = t + (u << 8);
    int k = idx >> 3, c4 = idx & 7;
    float4 v = *(const float4*)&Wn[(k0 + k) * 32 + (c4 << 2)];
    int cb = c4 << 2;
    Wt[(cb + 0) * 264 + k] = hubf(v.x);
    Wt[(cb + 1) * 264 + k] = hubf(v.y);
    Wt[(cb + 2) * 264 + k] = hubf(v.z);
    Wt[(cb + 3) * 264 + k] = hubf(v.w);
  }
  if (t < 256) Wsl[t] = Ws[k0 + t];
  __syncthreads();
  int wv = t >> 6, ln2 = t & 63;
  int m31 = ln2 & 31, hi2 = ln2 >> 5;
  f32x16 C = {};
#pragma unroll
  for (int kc = 0; kc < 64; kc += 16) {
    int ko = (wv << 6) + kc + (hi2 << 3);
    bf16x8 af = *(const bf16x8*)(As + m31 * 264 + ko);
    bf16x8 bfv = *(const bf16x8*)(Wt + m31 * 264 + ko);
    C = __builtin_amdgcn_mfma_f32_32x32x16_bf16(af, bfv, C, 0, 0, 0);
  }
  float spn = 0.f;
  if (t < 32) {
#pragma unroll 4
    for (int kk = 0; kk < 256; kk += 8) {
      bf16x8 avv = *(const bf16x8*)(As + t * 264 + kk);
#pragma unroll
      for (int e = 0; e < 8; ++e)
        spn += bfup((unsigned short)avv[e]) * Wsl[kk + e];
    }
  }
  __syncthreads();
  float* sl = slots + (wv << 10);
#pragma unroll
  for (int rr = 0; rr < 16; ++rr) {
    int arow = (rr & 3) + ((rr >> 2) << 3) + (hi2 << 2);
    sl[arow * 32 + m31] = C[rr];
  }
  __syncthreads();
#pragma unroll
  for (int u = 0; u < 4; ++u) {
    int idx = t + (u << 8);
    part[s * 262144 + (row0 << 5) + idx] =
        slots[idx] + slots[1024 + idx] + slots[2048 + idx] + slots[3072 + idx];
  }
  if (t < 32) partS[s * 8192 + row0 + t] = spn;
}

// One block per batch; entry fuses the split-K reduce (own batch slice).
// Chart as NORMALIZED X = exp(cn - rowmax) in LDS (transposed, stride 529).
// Per stage (3 barriers): [prefetch + in-wave P1 + P2] B1 [P3] B2 [out+renorm] B3
// Rbf held PERSISTENTLY in VGPRs of waves 0-3 (launch_bounds(1024,4) -> 128 cap).
// LDS 160704 B (layout as R15).
__global__ __launch_bounds__(1024, 4) void k_chain9(
    const float* __restrict__ part, const float* __restrict__ partS,
    const float* __restrict__ bn, const float* __restrict__ bs,
    float* __restrict__ node, float* __restrict__ span,
    const float* __restrict__ D, const unsigned short* __restrict__ Rbf,
    const int* __restrict__ sm, const float* __restrict__ rootm,
    float* __restrict__ out) {
  extern __shared__ char lds[];
  float* Xt = (float*)lds;
  char* Sb = lds + 67712;
  float* slots = (float*)(lds + 133376);
  int* T2i = (int*)(lds + 150272);
  float* maxv = (float*)(lds + 158464);
  float* G = (float*)(lds + 160576);
  const int t = threadIdx.x;
  const int b = blockIdx.x;
  const int w = t >> 6, ln = t & 63;
  const int pq = ln & 31, hi = ln >> 5, jb = hi << 3;
  const int rowB = b * 32;

  // ---- persistent Rbf fragments (waves 0-3): 64 VGPRs, live all stages ----
  BFU rb[16];
  if (w < 4) {
#pragma unroll
    for (int tt = 0; tt < 16; ++tt)
      rb[tt].v = *(const bf16x8*)(Rbf + (((w << 4) + tt) << 9) + (ln << 3));
  }

  // ---- entry: fused split-K reduce for this batch (node, span) ----
  {
    int base = b << 15;
#pragma unroll
    for (int k = 0; k < 8; ++k) {
      int idx = t + (k << 10);
      float4 v0 = *(const float4*)&part[base + (idx << 2)];
      float4 v1 = *(const float4*)&part[262144 + base + (idx << 2)];
      float4 v2 = *(const float4*)&part[524288 + base + (idx << 2)];
      float4 v3 = *(const float4*)&part[786432 + base + (idx << 2)];
      float4 bb = *(const float4*)&bn[(idx << 2) & 31];
      *(float4*)&node[base + (idx << 2)] =
          make_float4(v0.x + v1.x + v2.x + v3.x + bb.x,
                      v0.y + v1.y + v2.y + v3.y + bb.y,
                      v0.z + v1.z + v2.z + v3.z + bb.z,
                      v0.w + v1.w + v2.w + v3.w + bb.w);
    }
    int row = (b << 10) + t;
    span[row] = bs[0] + partS[row] + partS[8192 + row] +
                partS[16384 + row] + partS[24576 + row];
    float* z = (float*)lds;
    for (int idx = t; idx < 16928; idx += 1024) z[idx] = 0.f;
  }
  __syncthreads();
  // ---- diagonal init from node & D ----
  {
    int l = t >> 5, a = t & 31;
    float nd = node[(b << 15) + (l << 10) + (l << 5) + a];
    float dv = nd + nd + D[(rowB + l) * 32 + a];
    float m = dv;
#pragma unroll
    for (int s = 16; s >= 1; s >>= 1) m = fmaxf(m, __shfl_xor(m, s, 32));
    int off = l * (65 - l) / 2;
    Xt[a * 529 + off] = __expf(dv - m);
    if (a == 0) maxv[off] = m;
  }
  __syncthreads();

  for (int i = 1; i < 32; ++i) {
    const int nT = 32 - i;
    float nv = 0.f, sv = 0.f;
    {
      int cell = t >> 5;
      if (cell < nT) {
        nv = node[(rowB + cell) * 1024 + (cell + i) * 32 + (t & 31)];
        sv = span[(rowB + cell) * 32 + (cell + i)];
      }
    }
    // ---- in-wave P1 ----
    {
      int ct = hi ? 16 + w : w;
      bool on = (ct < nT) && (pq < i);
      float gj = -3.0e38f; int rc = 0;
      if (on) {
        int m2 = ct + pq + 1;
        rc = m2 * (65 - m2) / 2 + (i - 1 - pq);
        gj = maxv[ct * (65 - ct) / 2 + pq] + maxv[rc];
      }
      float gm = gj;
#pragma unroll
      for (int s = 16; s >= 1; s >>= 1) gm = fmaxf(gm, __shfl_xor(gm, s, 32));
      if (ct < nT) {
        float sc = on ? __expf(gj - gm) : 0.f;
        T2i[(ct << 6) + (pq << 1)] = __float_as_int(sc);
        T2i[(ct << 6) + (pq << 1) + 1] = on ? rc : 0;
        if (pq == 0) G[ct] = gm;
      }
    }
    // ---- P2 ----
#pragma unroll 1
    for (int half = 0; half < 2; ++half) {
      int cg = (half << 4) + w;
      if (cg >= nT) break;
      const float* xlb = Xt + pq * 529 + cg * (65 - cg) / 2;
      const float* xrr = Xt + pq * 529;
      f32x16 Sacc = {};
#pragma unroll
      for (int kk = 0; kk < 2; ++kk) {
        if (kk == 1 && i <= 16) break;
        int j0 = (kk << 4);
        const int4* t4 = (const int4*)(T2i + (cg << 6) + ((j0 + jb) << 1));
        BFU ua, ub;
#pragma unroll
        for (int r2 = 0; r2 < 4; ++r2) {
          int4 e = t4[r2];
          int j = j0 + jb + (r2 << 1);
          float a0 = xlb[j] * __int_as_float(e.x);
          float a1 = xlb[j + 1] * __int_as_float(e.z);
          ua.u[r2] = pk2bf(a0, a1);
          ub.u[r2] = pk2bf(xrr[e.y], xrr[e.w]);
        }
        Sacc = __builtin_amdgcn_mfma_f32_32x32x16_bf16(ua.v, ub.v, Sacc, 0, 0, 0);
      }
      char* sbp = Sb + cg * 2052;
#pragma unroll
      for (int rr = 0; rr < 16; rr += 2) {
        unsigned pk = pk2bf(Sacc[rr], Sacc[rr + 1]);
        int p0 = (rr & 3) + ((rr >> 2) << 3) + (hi << 2);
        int sw = (((pq >> 3) & 1) << 4) ^ (((p0 >> 2) & 1) << 2);
        int wd0 = (((p0 << 4) + (pq >> 1)) ^ sw);
        int wd1 = wd0 ^ 16;
        *(unsigned short*)(sbp + wd0 * 4 + ((pq & 1) << 1)) = (unsigned short)pk;
        *(unsigned short*)(sbp + wd1 * 4 + ((pq & 1) << 1)) = (unsigned short)(pk >> 16);
      }
    }
    __syncthreads();   // B1
    // ---- P3: inner = R * S; Rbf fragments from persistent VGPRs ----
    if (w < 4) {
      f32x16 C0 = {}, C1 = {};
#pragma unroll
      for (int tt = 0; tt < 16; ++tt) {
        int kst = (w << 4) + tt;
        int ko = (kst << 1) + hi;
        int p = ko >> 2, o = ko & 3;
        int wd = (((p << 4) + (o << 2)) ^ ((o & 1) << 4)) ^ (((p >> 2) & 1) << 2);
        const char* sp = Sb + pq * 2052 + wd * 4;
        BFU ub;
        ub.u[0] = *(const unsigned*)sp;
        ub.u[1] = *(const unsigned*)(sp + 4);
        ub.u[2] = *(const unsigned*)(sp + 8);
        ub.u[3] = *(const unsigned*)(sp + 12);
        if (tt & 1) C1 = __builtin_amdgcn_mfma_f32_32x32x16_bf16(rb[tt].v, ub.v, C1, 0, 0, 0);
        else        C0 = __builtin_amdgcn_mfma_f32_32x32x16_bf16(rb[tt].v, ub.v, C0, 0, 0, 0);
      }
      float* sl = slots + w * 1056;
#pragma unroll
      for (int rr = 0; rr < 16; ++rr) {
        int arow = (rr & 3) + ((rr >> 2) << 3) + (hi << 2);
        sl[pq * 33 + arow] = C0[rr] + C1[rr];
      }
    }
    __syncthreads();   // B2
    // ---- out + renorm fused ----
    {
      int cell = t >> 5, a = t & 31;
      if (cell < nT) {
        int so = cell * 33 + a;
        float pt = slots[so] + slots[1056 + so] + slots[2112 + so] + slots[3168 + so];
        float cnv = G[cell] + __logf(pt) + nv + nv + sv;
        float m = cnv;
#pragma unroll
        for (int s = 16; s >= 1; s >>= 1) m = fmaxf(m, __shfl_xor(m, s, 32));
        int ix = cell * (65 - cell) / 2 + i;
        Xt[a * 529 + ix] = __expf(cnv - m);
        if (a == 0) maxv[ix] = m;
      }
    }
    __syncthreads();   // B3
  }
  // ---- logits ----
  if (t < 32) {
    int len = 0;
#pragma unroll
    for (int l = 0; l < 32; ++l) len += sm[b * 32 + l];
    int e = len - 1;
    float cv = maxv[e] + __logf(Xt[t * 529 + e]) - node[(rowB * 32 + e) * 32 + t];
    out[b * 32 + t] = cv + (rootm[t] - 1.0f) * 1e10f;
  }
}

extern "C" void kernel_launch(void* const* d_in, const int* in_sizes, int n_in,
                              void* d_out, int out_size, void* d_ws, size_t ws_size,
                              hipStream_t stream) {
  const float* ph    = (const float*)d_in[0];
  const float* sh    = (const float*)d_in[1];
  const int*   sm    = (const int*)  d_in[2];
  const float* Wp    = (const float*)d_in[3];
  const float* bp    = (const float*)d_in[4];
  const float* Wn    = (const float*)d_in[5];
  const float* bn    = (const float*)d_in[6];
  const float* Ws    = (const float*)d_in[7];
  const float* bs    = (const float*)d_in[8];
  const float* rs    = (const float*)d_in[9];
  const float* pu    = (const float*)d_in[10];
  const float* rootm = (const float*)d_in[11];
  const float* pm    = (const float*)d_in[12];
  const float* rm    = (const float*)d_in[13];
  const float* pum   = (const float*)d_in[14];
  float* out = (float*)d_out;

  float* ws    = (float*)d_ws;
  float* node  = ws + NODE_OFF;
  float* span  = ws + SPAN_OFF;
  float* D     = ws + D_OFF;
  unsigned short* Rbf = (unsigned short*)(ws + RBF_OFF);
  float* part  = ws + PART_OFF;
  float* partS = ws + PARTS_OFF;

  hipFuncSetAttribute((const void*)k_chain9,
                      hipFuncAttributeMaxDynamicSharedMemorySize, 160704);
  k_pre<<<1408, 256, 0, stream>>>(ph, Wn, Ws, sh, Wp, bp, pm, pu, pum, rs, rm,
                                  part, partS, D, Rbf);
  k_chain9<<<8, 1024, 160704, stream>>>(part, partS, bn, bs, node, span, D, Rbf,
                                        sm, rootm, out);
}

// Round 18
// 106.835 us; speedup vs baseline: 2.0539x; 1.2490x over previous
//
#include <hip/hip_runtime.h>
#include <math.h>

// B=8, L=32, H=1024, N=32
// ws layout (floats):
#define NODE_OFF   0          // 8192*32
#define SPAN_OFF   262144     // 8192
#define D_OFF      270336     // 256*32
#define RBF_OFF    278528     // 32768 halfs: frag-order bf16 exp(rules)
#define PART_OFF   294912     // 4*262144 split-K node partials
#define PARTS_OFF  1343488    // 4*8192 split-K span partials

typedef short bf16x8 __attribute__((ext_vector_type(8)));
typedef float f32x16 __attribute__((ext_vector_type(16)));

union BFU { unsigned u[4]; bf16x8 v; };

__device__ inline short f2bf(float f) {            // RNE f32->bf16
  union { float f; unsigned u; } v; v.f = f;
  unsigned r = (v.u + 0x7FFFu + ((v.u >> 16) & 1u)) >> 16;
  return (short)r;
}
__device__ __forceinline__ unsigned short hubf(float f) {  // half-up round
  return (unsigned short)((__float_as_uint(f) + 0x8000u) >> 16);
}
__device__ __forceinline__ float bfup(unsigned short u) {
  return __uint_as_float(((unsigned)u) << 16);
}
__device__ __forceinline__ unsigned pk2bf(float lo, float hi) {
  unsigned r;
  asm("v_cvt_pk_bf16_f32 %0, %1, %2" : "=v"(r) : "v"(lo), "v"(hi));
  return r;
}

// Fused front kernel, 1408 blocks x 256:
//  0..1023: node split-K GEMM via MFMA (256 rowgroups x 32 rows x 4 k-slices)
//  1024..1279: posnode + D    1280..1407: Rbf swizzle
__global__ __launch_bounds__(256) void k_pre(
    const float* __restrict__ ph, const float* __restrict__ Wn,
    const float* __restrict__ Ws, const float* __restrict__ sh,
    const float* __restrict__ Wp, const float* __restrict__ bp,
    const float* __restrict__ pmask, const float* __restrict__ pu,
    const float* __restrict__ pum, const float* __restrict__ rs,
    const float* __restrict__ rm, float* __restrict__ part,
    float* __restrict__ partS, float* __restrict__ D,
    unsigned short* __restrict__ Rbf) {
  __shared__ float smem[8704];   // 34,816 B
  int t = threadIdx.x;
  int bid = blockIdx.x;
  if (bid >= 1280) {  // ---- Rbf: frag-order bf16 of exp(masked rules) ----
    int idx = ((bid - 1280) << 8) + t;       // [kst(64)][lane(64)][r(8)]
    int kst = idx >> 9, ln = (idx >> 3) & 63, r = idx & 7;
    int a = ln & 31;
    int kp = kst * 16 + ((ln >> 5) << 3) + r;   // k' = p*32+q
    float v = __expf(rs[a * 1024 + kp] + (rm[a * 1024 + kp] - 1.0f) * 1e10f);
    Rbf[idx] = (unsigned short)f2bf(v);
    return;
  }
  if (bid >= 1024) {  // ---- posnode + D ----
    float* rowl = smem;
    float* partl = smem + 1024;
    float* posn = smem + 1288;
    int row = bid - 1024;
#pragma unroll
    for (int k = 0; k < 4; ++k) rowl[t + 256 * k] = sh[row * 1024 + t + 256 * k];
    __syncthreads();
    int c = t & 31, seg = t >> 5;
    float pacc = 0.f;
    for (int hh = 0; hh < 128; ++hh)
      pacc += rowl[seg * 128 + hh] * Wp[(seg * 128 + hh) * 32 + c];
    partl[seg * 33 + c] = pacc;
    __syncthreads();
    if (t < 32) {
      float s = 0.f;
#pragma unroll
      for (int k = 0; k < 8; ++k) s += partl[k * 33 + t];
      posn[t] = s + bp[t] + (pmask[t] - 1.0f) * 1e10f;
    }
    __syncthreads();
    if (t < 32) {
      float mq = posn[t];
#pragma unroll
      for (int m = 16; m >= 1; m >>= 1) mq = fmaxf(mq, __shfl_xor(mq, m, 32));
      float sum = 0.f;
#pragma unroll 8
      for (int q = 0; q < 32; ++q)
        sum += __expf(pu[t * 32 + q] + (pum[t * 32 + q] - 1.0f) * 1e15f + posn[q] - mq);
      D[row * 32 + t] = mq + __logf(sum);
    }
    return;
  }
  // ---- node split-K GEMM via MFMA: 32 rows x 256 K per block ----
  unsigned short* As = (unsigned short*)smem;
  unsigned short* Wt = ((unsigned short*)smem) + 8448;
  float* Wsl = smem + 8448;
  float* slots = smem;
  int rg = bid >> 2, s = bid & 3;
  int row0 = rg << 5, k0 = s << 8;
#pragma unroll
  for (int u = 0; u < 8; ++u) {
    int idx = t + (u << 8);
    int r = idx >> 6, f4 = idx & 63;
    float4 v = *(const float4*)&ph[(row0 + r) * 1024 + k0 + (f4 << 2)];
    unsigned* dst = (unsigned*)(As + r * 264 + (f4 << 2));
    dst[0] = pk2bf(v.x, v.y);
    dst[1] = pk2bf(v.z, v.w);
  }
#pragma unroll
  for (int u = 0; u < 8; ++u) {
    int idx = t + (u << 8);
    int k = idx >> 3, c4 = idx & 7;
    float4 v = *(const float4*)&Wn[(k0 + k) * 32 + (c4 << 2)];
    int cb = c4 << 2;
    Wt[(cb + 0) * 264 + k] = hubf(v.x);
    Wt[(cb + 1) * 264 + k] = hubf(v.y);
    Wt[(cb + 2) * 264 + k] = hubf(v.z);
    Wt[(cb + 3) * 264 + k] = hubf(v.w);
  }
  if (t < 256) Wsl[t] = Ws[k0 + t];
  __syncthreads();
  int wv = t >> 6, ln2 = t & 63;
  int m31 = ln2 & 31, hi2 = ln2 >> 5;
  f32x16 C = {};
#pragma unroll
  for (int kc = 0; kc < 64; kc += 16) {
    int ko = (wv << 6) + kc + (hi2 << 3);
    bf16x8 af = *(const bf16x8*)(As + m31 * 264 + ko);
    bf16x8 bfv = *(const bf16x8*)(Wt + m31 * 264 + ko);
    C = __builtin_amdgcn_mfma_f32_32x32x16_bf16(af, bfv, C, 0, 0, 0);
  }
  float spn = 0.f;
  if (t < 32) {
#pragma unroll 4
    for (int kk = 0; kk < 256; kk += 8) {
      bf16x8 avv = *(const bf16x8*)(As + t * 264 + kk);
#pragma unroll
      for (int e = 0; e < 8; ++e)
        spn += bfup((unsigned short)avv[e]) * Wsl[kk + e];
    }
  }
  __syncthreads();
  float* sl = slots + (wv << 10);
#pragma unroll
  for (int rr = 0; rr < 16; ++rr) {
    int arow = (rr & 3) + ((rr >> 2) << 3) + (hi2 << 2);
    sl[arow * 32 + m31] = C[rr];
  }
  __syncthreads();
#pragma unroll
  for (int u = 0; u < 4; ++u) {
    int idx = t + (u << 8);
    part[s * 262144 + (row0 << 5) + idx] =
        slots[idx] + slots[1024 + idx] + slots[2048 + idx] + slots[3072 + idx];
  }
  if (t < 32) partS[s * 8192 + row0 + t] = spn;
}

// One block per batch; entry fuses the split-K reduce (own batch slice).
// Chart as NORMALIZED X = exp(cn - rowmax) in LDS (transposed, stride 529).
// Per stage (3 barriers): [prefetch + in-wave P1 + P2] B1 [P3 8-wave] B2
// [out+renorm] B3.  P3 k-split 8 ways; partials stored bf16 (non-negative,
// no cancellation).  Rbf frags persistent in VGPRs of waves 0-7 (8 each).
// LDS 161216 B:
//   Xt    f32[32*529]    @0
//   Sb    32 x 2052 B    @67712    (bf16 S, XOR-swizzled)
//   slotb u16[8][1088]   @133376   (bf16 P3 partials, 17408 B)
//   T2    int2[32][32]   @150784
//   maxv  f32[528]       @158976
//   G     f32[32]        @161088
__global__ __launch_bounds__(1024, 4) void k_chain9(
    const float* __restrict__ part, const float* __restrict__ partS,
    const float* __restrict__ bn, const float* __restrict__ bs,
    float* __restrict__ node, float* __restrict__ span,
    const float* __restrict__ D, const unsigned short* __restrict__ Rbf,
    const int* __restrict__ sm, const float* __restrict__ rootm,
    float* __restrict__ out) {
  extern __shared__ char lds[];
  float* Xt = (float*)lds;
  char* Sb = lds + 67712;
  unsigned short* slotb = (unsigned short*)(lds + 133376);
  int* T2i = (int*)(lds + 150784);
  float* maxv = (float*)(lds + 158976);
  float* G = (float*)(lds + 161088);
  const int t = threadIdx.x;
  const int b = blockIdx.x;
  const int w = t >> 6, ln = t & 63;
  const int pq = ln & 31, hi = ln >> 5, jb = hi << 3;
  const int rowB = b * 32;

  // ---- persistent Rbf fragments (waves 0-7): 8 frags = 32 VGPRs each ----
  BFU rb[8];
  if (w < 8) {
#pragma unroll
    for (int tt = 0; tt < 8; ++tt)
      rb[tt].v = *(const bf16x8*)(Rbf + (((w << 3) + tt) << 9) + (ln << 3));
  }

  // ---- entry: fused split-K reduce for this batch (node, span) ----
  {
    int base = b << 15;
#pragma unroll
    for (int k = 0; k < 8; ++k) {
      int idx = t + (k << 10);
      float4 v0 = *(const float4*)&part[base + (idx << 2)];
      float4 v1 = *(const float4*)&part[262144 + base + (idx << 2)];
      float4 v2 = *(const float4*)&part[524288 + base + (idx << 2)];
      float4 v3 = *(const float4*)&part[786432 + base + (idx << 2)];
      float4 bb = *(const float4*)&bn[(idx << 2) & 31];
      *(float4*)&node[base + (idx << 2)] =
          make_float4(v0.x + v1.x + v2.x + v3.x + bb.x,
                      v0.y + v1.y + v2.y + v3.y + bb.y,
                      v0.z + v1.z + v2.z + v3.z + bb.z,
                      v0.w + v1.w + v2.w + v3.w + bb.w);
    }
    int row = (b << 10) + t;
    span[row] = bs[0] + partS[row] + partS[8192 + row] +
                partS[16384 + row] + partS[24576 + row];
    float* z = (float*)lds;
    for (int idx = t; idx < 16928; idx += 1024) z[idx] = 0.f;
  }
  __syncthreads();
  // ---- diagonal init from node & D ----
  {
    int l = t >> 5, a = t & 31;
    float nd = node[(b << 15) + (l << 10) + (l << 5) + a];
    float dv = nd + nd + D[(rowB + l) * 32 + a];
    float m = dv;
#pragma unroll
    for (int s = 16; s >= 1; s >>= 1) m = fmaxf(m, __shfl_xor(m, s, 32));
    int off = l * (65 - l) / 2;
    Xt[a * 529 + off] = __expf(dv - m);
    if (a == 0) maxv[off] = m;
  }
  __syncthreads();

  for (int i = 1; i < 32; ++i) {
    const int nT = 32 - i;
    float nv = 0.f, sv = 0.f;
    {
      int cell = t >> 5;
      if (cell < nT) {
        nv = node[(rowB + cell) * 1024 + (cell + i) * 32 + (t & 31)];
        sv = span[(rowB + cell) * 32 + (cell + i)];
      }
    }
    // ---- in-wave P1 ----
    {
      int ct = hi ? 16 + w : w;
      bool on = (ct < nT) && (pq < i);
      float gj = -3.0e38f; int rc = 0;
      if (on) {
        int m2 = ct + pq + 1;
        rc = m2 * (65 - m2) / 2 + (i - 1 - pq);
        gj = maxv[ct * (65 - ct) / 2 + pq] + maxv[rc];
      }
      float gm = gj;
#pragma unroll
      for (int s = 16; s >= 1; s >>= 1) gm = fmaxf(gm, __shfl_xor(gm, s, 32));
      if (ct < nT) {
        float sc = on ? __expf(gj - gm) : 0.f;
        T2i[(ct << 6) + (pq << 1)] = __float_as_int(sc);
        T2i[(ct << 6) + (pq << 1) + 1] = on ? rc : 0;
        if (pq == 0) G[ct] = gm;
      }
    }
    // ---- P2 ----
#pragma unroll 1
    for (int half = 0; half < 2; ++half) {
      int cg = (half << 4) + w;
      if (cg >= nT) break;
      const float* xlb = Xt + pq * 529 + cg * (65 - cg) / 2;
      const float* xrr = Xt + pq * 529;
      f32x16 Sacc = {};
#pragma unroll
      for (int kk = 0; kk < 2; ++kk) {
        if (kk == 1 && i <= 16) break;
        int j0 = (kk << 4);
        const int4* t4 = (const int4*)(T2i + (cg << 6) + ((j0 + jb) << 1));
        BFU ua, ub;
#pragma unroll
        for (int r2 = 0; r2 < 4; ++r2) {
          int4 e = t4[r2];
          int j = j0 + jb + (r2 << 1);
          float a0 = xlb[j] * __int_as_float(e.x);
          float a1 = xlb[j + 1] * __int_as_float(e.z);
          ua.u[r2] = pk2bf(a0, a1);
          ub.u[r2] = pk2bf(xrr[e.y], xrr[e.w]);
        }
        Sacc = __builtin_amdgcn_mfma_f32_32x32x16_bf16(ua.v, ub.v, Sacc, 0, 0, 0);
      }
      char* sbp = Sb + cg * 2052;
#pragma unroll
      for (int rr = 0; rr < 16; rr += 2) {
        unsigned pk = pk2bf(Sacc[rr], Sacc[rr + 1]);
        int p0 = (rr & 3) + ((rr >> 2) << 3) + (hi << 2);
        int sw = (((pq >> 3) & 1) << 4) ^ (((p0 >> 2) & 1) << 2);
        int wd0 = (((p0 << 4) + (pq >> 1)) ^ sw);
        int wd1 = wd0 ^ 16;
        *(unsigned short*)(sbp + wd0 * 4 + ((pq & 1) << 1)) = (unsigned short)pk;
        *(unsigned short*)(sbp + wd1 * 4 + ((pq & 1) << 1)) = (unsigned short)(pk >> 16);
      }
    }
    __syncthreads();   // B1
    // ---- P3: inner = R * S, 8-wave k-split (2 waves/SIMD), bf16 partials ----
    if (w < 8) {
      f32x16 C0 = {}, C1 = {};
#pragma unroll
      for (int tt = 0; tt < 8; ++tt) {
        int kst = (w << 3) + tt;
        int ko = (kst << 1) + hi;
        int p = ko >> 2, o = ko & 3;
        int wd = (((p << 4) + (o << 2)) ^ ((o & 1) << 4)) ^ (((p >> 2) & 1) << 2);
        const char* sp = Sb + pq * 2052 + wd * 4;
        BFU ub;
        ub.u[0] = *(const unsigned*)sp;
        ub.u[1] = *(const unsigned*)(sp + 4);
        ub.u[2] = *(const unsigned*)(sp + 8);
        ub.u[3] = *(const unsigned*)(sp + 12);
        if (tt & 1) C1 = __builtin_amdgcn_mfma_f32_32x32x16_bf16(rb[tt].v, ub.v, C1, 0, 0, 0);
        else        C0 = __builtin_amdgcn_mfma_f32_32x32x16_bf16(rb[tt].v, ub.v, C0, 0, 0, 0);
      }
      // store bf16 partials: slot w, u32 packed pairs (arow even base)
      unsigned short* sl = slotb + w * 1088;
#pragma unroll
      for (int rr = 0; rr < 16; rr += 2) {
        int arow = (rr & 3) + ((rr >> 2) << 3) + (hi << 2);
        *(unsigned*)(sl + pq * 34 + arow) =
            pk2bf(C0[rr] + C1[rr], C0[rr + 1] + C1[rr + 1]);
      }
    }
    __syncthreads();   // B2
    // ---- out + renorm fused ----
    {
      int cell = t >> 5, a = t & 31;
      if (cell < nT) {
        int so = cell * 34 + a;
        float pt = 0.f;
#pragma unroll
        for (int k = 0; k < 8; ++k) pt += bfup(slotb[k * 1088 + so]);
        float cnv = G[cell] + __logf(pt) + nv + nv + sv;
        float m = cnv;
#pragma unroll
        for (int s = 16; s >= 1; s >>= 1) m = fmaxf(m, __shfl_xor(m, s, 32));
        int ix = cell * (65 - cell) / 2 + i;
        Xt[a * 529 + ix] = __expf(cnv - m);
        if (a == 0) maxv[ix] = m;
      }
    }
    __syncthreads();   // B3
  }
  // ---- logits ----
  if (t < 32) {
    int len = 0;
#pragma unroll
    for (int l = 0; l < 32; ++l) len += sm[b * 32 + l];
    int e = len - 1;
    float cv = maxv[e] + __logf(Xt[t * 529 + e]) - node[(rowB * 32 + e) * 32 + t];
    out[b * 32 + t] = cv + (rootm[t] - 1.0f) * 1e10f;
  }
}

extern "C" void kernel_launch(void* const* d_in, const int* in_sizes, int n_in,
                              void* d_out, int out_size, void* d_ws, size_t ws_size,
                              hipStream_t stream) {
  const float* ph    = (const float*)d_in[0];
  const float* sh    = (const float*)d_in[1];
  const int*   sm    = (const int*)  d_in[2];
  const float* Wp    = (const float*)d_in[3];
  const float* bp    = (const float*)d_in[4];
  const float* Wn    = (const float*)d_in[5];
  const float* bn    = (const float*)d_in[6];
  const float* Ws    = (const float*)d_in[7];
  const float* bs    = (const float*)d_in[8];
  const float* rs    = (const float*)d_in[9];
  const float* pu    = (const float*)d_in[10];
  const float* rootm = (const float*)d_in[11];
  const float* pm    = (const float*)d_in[12];
  const float* rm    = (const float*)d_in[13];
  const float* pum   = (const float*)d_in[14];
  float* out = (float*)d_out;

  float* ws    = (float*)d_ws;
  float* node  = ws + NODE_OFF;
  float* span  = ws + SPAN_OFF;
  float* D     = ws + D_OFF;
  unsigned short* Rbf = (unsigned short*)(ws + RBF_OFF);
  float* part  = ws + PART_OFF;
  float* partS = ws + PARTS_OFF;

  hipFuncSetAttribute((const void*)k_chain9,
                      hipFuncAttributeMaxDynamicSharedMemorySize, 161216);
  k_pre<<<1408, 256, 0, stream>>>(ph, Wn, Ws, sh, Wp, bp, pm, pu, pum, rs, rm,
                                  part, partS, D, Rbf);
  k_chain9<<<8, 1024, 161216, stream>>>(part, partS, bn, bs, node, span, D, Rbf,
                                        sm, rootm, out);
}

// Round 19
// 105.061 us; speedup vs baseline: 2.0886x; 1.0169x over previous
//
#include <hip/hip_runtime.h>
#include <math.h>

// B=8, L=32, H=1024, N=32
// ws layout (floats):
#define NODE_OFF   0          // 8192*32
#define SPAN_OFF   262144     // 8192
#define D_OFF      270336     // 256*32
#define RBF_OFF    278528     // 32768 halfs: frag-order bf16 exp(rules)
#define PART_OFF   294912     // 4*262144 split-K node partials
#define PARTS_OFF  1343488    // 4*8192 split-K span partials

typedef short bf16x8 __attribute__((ext_vector_type(8)));
typedef float f32x16 __attribute__((ext_vector_type(16)));

union BFU { unsigned u[4]; bf16x8 v; };

__device__ inline short f2bf(float f) {            // RNE f32->bf16
  union { float f; unsigned u; } v; v.f = f;
  unsigned r = (v.u + 0x7FFFu + ((v.u >> 16) & 1u)) >> 16;
  return (short)r;
}
__device__ __forceinline__ unsigned short hubf(float f) {  // half-up round
  return (unsigned short)((__float_as_uint(f) + 0x8000u) >> 16);
}
__device__ __forceinline__ float bfup(unsigned short u) {
  return __uint_as_float(((unsigned)u) << 16);
}
__device__ __forceinline__ unsigned pk2bf(float lo, float hi) {
  unsigned r;
  asm("v_cvt_pk_bf16_f32 %0, %1, %2" : "=v"(r) : "v"(lo), "v"(hi));
  return r;
}

// Fused front kernel, 1408 blocks x 256:
//  0..1023: node split-K GEMM via MFMA (256 rowgroups x 32 rows x 4 k-slices)
//  1024..1279: posnode + D    1280..1407: Rbf swizzle
__global__ __launch_bounds__(256) void k_pre(
    const float* __restrict__ ph, const float* __restrict__ Wn,
    const float* __restrict__ Ws, const float* __restrict__ sh,
    const float* __restrict__ Wp, const float* __restrict__ bp,
    const float* __restrict__ pmask, const float* __restrict__ pu,
    const float* __restrict__ pum, const float* __restrict__ rs,
    const float* __restrict__ rm, float* __restrict__ part,
    float* __restrict__ partS, float* __restrict__ D,
    unsigned short* __restrict__ Rbf) {
  __shared__ float smem[8704];   // 34,816 B
  int t = threadIdx.x;
  int bid = blockIdx.x;
  if (bid >= 1280) {  // ---- Rbf: frag-order bf16 of exp(masked rules) ----
    int idx = ((bid - 1280) << 8) + t;       // [kst(64)][lane(64)][r(8)]
    int kst = idx >> 9, ln = (idx >> 3) & 63, r = idx & 7;
    int a = ln & 31;
    int kp = kst * 16 + ((ln >> 5) << 3) + r;   // k' = p*32+q
    float v = __expf(rs[a * 1024 + kp] + (rm[a * 1024 + kp] - 1.0f) * 1e10f);
    Rbf[idx] = (unsigned short)f2bf(v);
    return;
  }
  if (bid >= 1024) {  // ---- posnode + D ----
    float* rowl = smem;
    float* partl = smem + 1024;
    float* posn = smem + 1288;
    int row = bid - 1024;
#pragma unroll
    for (int k = 0; k < 4; ++k) rowl[t + 256 * k] = sh[row * 1024 + t + 256 * k];
    __syncthreads();
    int c = t & 31, seg = t >> 5;
    float pacc = 0.f;
    for (int hh = 0; hh < 128; ++hh)
      pacc += rowl[seg * 128 + hh] * Wp[(seg * 128 + hh) * 32 + c];
    partl[seg * 33 + c] = pacc;
    __syncthreads();
    if (t < 32) {
      float s = 0.f;
#pragma unroll
      for (int k = 0; k < 8; ++k) s += partl[k * 33 + t];
      posn[t] = s + bp[t] + (pmask[t] - 1.0f) * 1e10f;
    }
    __syncthreads();
    if (t < 32) {
      float mq = posn[t];
#pragma unroll
      for (int m = 16; m >= 1; m >>= 1) mq = fmaxf(mq, __shfl_xor(mq, m, 32));
      float sum = 0.f;
#pragma unroll 8
      for (int q = 0; q < 32; ++q)
        sum += __expf(pu[t * 32 + q] + (pum[t * 32 + q] - 1.0f) * 1e15f + posn[q] - mq);
      D[row * 32 + t] = mq + __logf(sum);
    }
    return;
  }
  // ---- node split-K GEMM via MFMA: 32 rows x 256 K per block ----
  unsigned short* As = (unsigned short*)smem;
  unsigned short* Wt = ((unsigned short*)smem) + 8448;
  float* Wsl = smem + 8448;
  float* slots = smem;
  int rg = bid >> 2, s = bid & 3;
  int row0 = rg << 5, k0 = s << 8;
#pragma unroll
  for (int u = 0; u < 8; ++u) {
    int idx = t + (u << 8);
    int r = idx >> 6, f4 = idx & 63;
    float4 v = *(const float4*)&ph[(row0 + r) * 1024 + k0 + (f4 << 2)];
    unsigned* dst = (unsigned*)(As + r * 264 + (f4 << 2));
    dst[0] = pk2bf(v.x, v.y);
    dst[1] = pk2bf(v.z, v.w);
  }
#pragma unroll
  for (int u = 0; u < 8; ++u) {
    int idx = t + (u << 8);
    int k = idx >> 3, c4 = idx & 7;
    float4 v = *(const float4*)&Wn[(k0 + k) * 32 + (c4 << 2)];
    int cb = c4 << 2;
    Wt[(cb + 0) * 264 + k] = hubf(v.x);
    Wt[(cb + 1) * 264 + k] = hubf(v.y);
    Wt[(cb + 2) * 264 + k] = hubf(v.z);
    Wt[(cb + 3) * 264 + k] = hubf(v.w);
  }
  if (t < 256) Wsl[t] = Ws[k0 + t];
  __syncthreads();
  int wv = t >> 6, ln2 = t & 63;
  int m31 = ln2 & 31, hi2 = ln2 >> 5;
  f32x16 C = {};
#pragma unroll
  for (int kc = 0; kc < 64; kc += 16) {
    int ko = (wv << 6) + kc + (hi2 << 3);
    bf16x8 af = *(const bf16x8*)(As + m31 * 264 + ko);
    bf16x8 bfv = *(const bf16x8*)(Wt + m31 * 264 + ko);
    C = __builtin_amdgcn_mfma_f32_32x32x16_bf16(af, bfv, C, 0, 0, 0);
  }
  float spn = 0.f;
  if (t < 32) {
#pragma unroll 4
    for (int kk = 0; kk < 256; kk += 8) {
      bf16x8 avv = *(const bf16x8*)(As + t * 264 + kk);
#pragma unroll
      for (int e = 0; e < 8; ++e)
        spn += bfup((unsigned short)avv[e]) * Wsl[kk + e];
    }
  }
  __syncthreads();
  float* sl = slots + (wv << 10);
#pragma unroll
  for (int rr = 0; rr < 16; ++rr) {
    int arow = (rr & 3) + ((rr >> 2) << 3) + (hi2 << 2);
    sl[arow * 32 + m31] = C[rr];
  }
  __syncthreads();
#pragma unroll
  for (int u = 0; u < 4; ++u) {
    int idx = t + (u << 8);
    part[s * 262144 + (row0 << 5) + idx] =
        slots[idx] + slots[1024 + idx] + slots[2048 + idx] + slots[3072 + idx];
  }
  if (t < 32) partS[s * 8192 + row0 + t] = spn;
}

// One block per batch; entry fuses the split-K reduce (own batch slice).
// Chart as NORMALIZED X = exp(cn - rowmax) in LDS (transposed, stride 529).
// Per stage (3 barriers): [prefetch + in-wave P1 + P2] B1 [P3 8-wave, b128
// Sb frag reads] B2 [out+renorm] B3.
// LDS 161600 B:
//   Xt    f32[32*529]    @0
//   Sb    32 x 2064 B    @67712    (bf16 S, XOR-swizzled, 16B-aligned rows)
//   slotb u16[8][1088]   @133760   (bf16 P3 partials)
//   T2    int2[32][32]   @151168
//   maxv  f32[528]       @159360
//   G     f32[32]        @161472
__global__ __launch_bounds__(1024, 4) void k_chain9(
    const float* __restrict__ part, const float* __restrict__ partS,
    const float* __restrict__ bn, const float* __restrict__ bs,
    float* __restrict__ node, float* __restrict__ span,
    const float* __restrict__ D, const unsigned short* __restrict__ Rbf,
    const int* __restrict__ sm, const float* __restrict__ rootm,
    float* __restrict__ out) {
  extern __shared__ char lds[];
  float* Xt = (float*)lds;
  char* Sb = lds + 67712;
  unsigned short* slotb = (unsigned short*)(lds + 133760);
  int* T2i = (int*)(lds + 151168);
  float* maxv = (float*)(lds + 159360);
  float* G = (float*)(lds + 161472);
  const int t = threadIdx.x;
  const int b = blockIdx.x;
  const int w = t >> 6, ln = t & 63;
  const int pq = ln & 31, hi = ln >> 5, jb = hi << 3;
  const int rowB = b * 32;

  // ---- persistent Rbf fragments (waves 0-7): 8 frags = 32 VGPRs each ----
  BFU rb[8];
  if (w < 8) {
#pragma unroll
    for (int tt = 0; tt < 8; ++tt)
      rb[tt].v = *(const bf16x8*)(Rbf + (((w << 3) + tt) << 9) + (ln << 3));
  }

  // ---- entry: fused split-K reduce for this batch (node, span) ----
  {
    int base = b << 15;
#pragma unroll
    for (int k = 0; k < 8; ++k) {
      int idx = t + (k << 10);
      float4 v0 = *(const float4*)&part[base + (idx << 2)];
      float4 v1 = *(const float4*)&part[262144 + base + (idx << 2)];
      float4 v2 = *(const float4*)&part[524288 + base + (idx << 2)];
      float4 v3 = *(const float4*)&part[786432 + base + (idx << 2)];
      float4 bb = *(const float4*)&bn[(idx << 2) & 31];
      *(float4*)&node[base + (idx << 2)] =
          make_float4(v0.x + v1.x + v2.x + v3.x + bb.x,
                      v0.y + v1.y + v2.y + v3.y + bb.y,
                      v0.z + v1.z + v2.z + v3.z + bb.z,
                      v0.w + v1.w + v2.w + v3.w + bb.w);
    }
    int row = (b << 10) + t;
    span[row] = bs[0] + partS[row] + partS[8192 + row] +
                partS[16384 + row] + partS[24576 + row];
    float* z = (float*)lds;
    for (int idx = t; idx < 16928; idx += 1024) z[idx] = 0.f;
  }
  __syncthreads();
  // ---- diagonal init from node & D ----
  {
    int l = t >> 5, a = t & 31;
    float nd = node[(b << 15) + (l << 10) + (l << 5) + a];
    float dv = nd + nd + D[(rowB + l) * 32 + a];
    float m = dv;
#pragma unroll
    for (int s = 16; s >= 1; s >>= 1) m = fmaxf(m, __shfl_xor(m, s, 32));
    int off = l * (65 - l) / 2;
    Xt[a * 529 + off] = __expf(dv - m);
    if (a == 0) maxv[off] = m;
  }
  __syncthreads();

  for (int i = 1; i < 32; ++i) {
    const int nT = 32 - i;
    float nv = 0.f, sv = 0.f;
    {
      int cell = t >> 5;
      if (cell < nT) {
        nv = node[(rowB + cell) * 1024 + (cell + i) * 32 + (t & 31)];
        sv = span[(rowB + cell) * 32 + (cell + i)];
      }
    }
    // ---- in-wave P1 ----
    {
      int ct = hi ? 16 + w : w;
      bool on = (ct < nT) && (pq < i);
      float gj = -3.0e38f; int rc = 0;
      if (on) {
        int m2 = ct + pq + 1;
        rc = m2 * (65 - m2) / 2 + (i - 1 - pq);
        gj = maxv[ct * (65 - ct) / 2 + pq] + maxv[rc];
      }
      float gm = gj;
#pragma unroll
      for (int s = 16; s >= 1; s >>= 1) gm = fmaxf(gm, __shfl_xor(gm, s, 32));
      if (ct < nT) {
        float sc = on ? __expf(gj - gm) : 0.f;
        T2i[(ct << 6) + (pq << 1)] = __float_as_int(sc);
        T2i[(ct << 6) + (pq << 1) + 1] = on ? rc : 0;
        if (pq == 0) G[ct] = gm;
      }
    }
    // ---- P2 ----
#pragma unroll 1
    for (int half = 0; half < 2; ++half) {
      int cg = (half << 4) + w;
      if (cg >= nT) break;
      const float* xlb = Xt + pq * 529 + cg * (65 - cg) / 2;
      const float* xrr = Xt + pq * 529;
      f32x16 Sacc = {};
#pragma unroll
      for (int kk = 0; kk < 2; ++kk) {
        if (kk == 1 && i <= 16) break;
        int j0 = (kk << 4);
        const int4* t4 = (const int4*)(T2i + (cg << 6) + ((j0 + jb) << 1));
        BFU ua, ub;
#pragma unroll
        for (int r2 = 0; r2 < 4; ++r2) {
          int4 e = t4[r2];
          int j = j0 + jb + (r2 << 1);
          float a0 = xlb[j] * __int_as_float(e.x);
          float a1 = xlb[j + 1] * __int_as_float(e.z);
          ua.u[r2] = pk2bf(a0, a1);
          ub.u[r2] = pk2bf(xrr[e.y], xrr[e.w]);
        }
        Sacc = __builtin_amdgcn_mfma_f32_32x32x16_bf16(ua.v, ub.v, Sacc, 0, 0, 0);
      }
      char* sbp = Sb + cg * 2064;
#pragma unroll
      for (int rr = 0; rr < 16; rr += 2) {
        unsigned pk = pk2bf(Sacc[rr], Sacc[rr + 1]);
        int p0 = (rr & 3) + ((rr >> 2) << 3) + (hi << 2);
        int sw = (((pq >> 3) & 1) << 4) ^ (((p0 >> 2) & 1) << 2);
        int wd0 = (((p0 << 4) + (pq >> 1)) ^ sw);
        int wd1 = wd0 ^ 16;
        *(unsigned short*)(sbp + wd0 * 4 + ((pq & 1) << 1)) = (unsigned short)pk;
        *(unsigned short*)(sbp + wd1 * 4 + ((pq & 1) << 1)) = (unsigned short)(pk >> 16);
      }
    }
    __syncthreads();   // B1
    // ---- P3: inner = R * S, 8-wave k-split; Sb frags via single b128 ----
    if (w < 8) {
      f32x16 C0 = {}, C1 = {};
#pragma unroll
      for (int tt = 0; tt < 8; ++tt) {
        int kst = (w << 3) + tt;
        int ko = (kst << 1) + hi;
        int p = ko >> 2, o = ko & 3;
        int wd = (((p << 4) + (o << 2)) ^ ((o & 1) << 4)) ^ (((p >> 2) & 1) << 2);
        // rows 16B-aligned (stride 2064), wd%4==0 -> 16B-aligned b128 read
        const uint4* sp = (const uint4*)(Sb + pq * 2064 + wd * 4);
        BFU ub;
        *(uint4*)&ub.u[0] = *sp;
        if (tt & 1) C1 = __builtin_amdgcn_mfma_f32_32x32x16_bf16(rb[tt].v, ub.v, C1, 0, 0, 0);
        else        C0 = __builtin_amdgcn_mfma_f32_32x32x16_bf16(rb[tt].v, ub.v, C0, 0, 0, 0);
      }
      unsigned short* sl = slotb + w * 1088;
#pragma unroll
      for (int rr = 0; rr < 16; rr += 2) {
        int arow = (rr & 3) + ((rr >> 2) << 3) + (hi << 2);
        *(unsigned*)(sl + pq * 34 + arow) =
            pk2bf(C0[rr] + C1[rr], C0[rr + 1] + C1[rr + 1]);
      }
    }
    __syncthreads();   // B2
    // ---- out + renorm fused ----
    {
      int cell = t >> 5, a = t & 31;
      if (cell < nT) {
        int so = cell * 34 + a;
        float pt = 0.f;
#pragma unroll
        for (int k = 0; k < 8; ++k) pt += bfup(slotb[k * 1088 + so]);
        float cnv = G[cell] + __logf(pt) + nv + nv + sv;
        float m = cnv;
#pragma unroll
        for (int s = 16; s >= 1; s >>= 1) m = fmaxf(m, __shfl_xor(m, s, 32));
        int ix = cell * (65 - cell) / 2 + i;
        Xt[a * 529 + ix] = __expf(cnv - m);
        if (a == 0) maxv[ix] = m;
      }
    }
    __syncthreads();   // B3
  }
  // ---- logits ----
  if (t < 32) {
    int len = 0;
#pragma unroll
    for (int l = 0; l < 32; ++l) len += sm[b * 32 + l];
    int e = len - 1;
    float cv = maxv[e] + __logf(Xt[t * 529 + e]) - node[(rowB * 32 + e) * 32 + t];
    out[b * 32 + t] = cv + (rootm[t] - 1.0f) * 1e10f;
  }
}

extern "C" void kernel_launch(void* const* d_in, const int* in_sizes, int n_in,
                              void* d_out, int out_size, void* d_ws, size_t ws_size,
                              hipStream_t stream) {
  const float* ph    = (const float*)d_in[0];
  const float* sh    = (const float*)d_in[1];
  const int*   sm    = (const int*)  d_in[2];
  const float* Wp    = (const float*)d_in[3];
  const float* bp    = (const float*)d_in[4];
  const float* Wn    = (const float*)d_in[5];
  const float* bn    = (const float*)d_in[6];
  const float* Ws    = (const float*)d_in[7];
  const float* bs    = (const float*)d_in[8];
  const float* rs    = (const float*)d_in[9];
  const float* pu    = (const float*)d_in[10];
  const float* rootm = (const float*)d_in[11];
  const float* pm    = (const float*)d_in[12];
  const float* rm    = (const float*)d_in[13];
  const float* pum   = (const float*)d_in[14];
  float* out = (float*)d_out;

  float* ws    = (float*)d_ws;
  float* node  = ws + NODE_OFF;
  float* span  = ws + SPAN_OFF;
  float* D     = ws + D_OFF;
  unsigned short* Rbf = (unsigned short*)(ws + RBF_OFF);
  float* part  = ws + PART_OFF;
  float* partS = ws + PARTS_OFF;

  hipFuncSetAttribute((const void*)k_chain9,
                      hipFuncAttributeMaxDynamicSharedMemorySize, 161600);
  k_pre<<<1408, 256, 0, stream>>>(ph, Wn, Ws, sh, Wp, bp, pm, pu, pum, rs, rm,
                                  part, partS, D, Rbf);
  k_chain9<<<8, 1024, 161600, stream>>>(part, partS, bn, bs, node, span, D, Rbf,
                                        sm, rootm, out);
}

// Round 20
// 103.426 us; speedup vs baseline: 2.1216x; 1.0158x over previous
//
#include <hip/hip_runtime.h>
#include <math.h>

// B=8, L=32, H=1024, N=32
// ws layout (floats):
#define NODE_OFF   0          // 8192*32
#define SPAN_OFF   262144     // 8192
#define D_OFF      270336     // 256*32
#define RBF_OFF    278528     // 32768 halfs: frag-order bf16 exp(rules)
#define PART_OFF   294912     // 4*262144 split-K node partials
#define PARTS_OFF  1343488    // 4*8192 split-K span partials

typedef short bf16x8 __attribute__((ext_vector_type(8)));
typedef float f32x16 __attribute__((ext_vector_type(16)));

union BFU { unsigned u[4]; bf16x8 v; };

__device__ inline short f2bf(float f) {            // RNE f32->bf16
  union { float f; unsigned u; } v; v.f = f;
  unsigned r = (v.u + 0x7FFFu + ((v.u >> 16) & 1u)) >> 16;
  return (short)r;
}
__device__ __forceinline__ unsigned short hubf(float f) {  // half-up round
  return (unsigned short)((__float_as_uint(f) + 0x8000u) >> 16);
}
__device__ __forceinline__ float bfup(unsigned short u) {
  return __uint_as_float(((unsigned)u) << 16);
}
__device__ __forceinline__ unsigned pk2bf(float lo, float hi) {
  unsigned r;
  asm("v_cvt_pk_bf16_f32 %0, %1, %2" : "=v"(r) : "v"(lo), "v"(hi));
  return r;
}

// Fused front kernel, 1408 blocks x 256:
//  0..1023: node split-K GEMM via MFMA (256 rowgroups x 32 rows x 4 k-slices)
//  1024..1279: posnode + D    1280..1407: Rbf swizzle
__global__ __launch_bounds__(256) void k_pre(
    const float* __restrict__ ph, const float* __restrict__ Wn,
    const float* __restrict__ Ws, const float* __restrict__ sh,
    const float* __restrict__ Wp, const float* __restrict__ bp,
    const float* __restrict__ pmask, const float* __restrict__ pu,
    const float* __restrict__ pum, const float* __restrict__ rs,
    const float* __restrict__ rm, float* __restrict__ part,
    float* __restrict__ partS, float* __restrict__ D,
    unsigned short* __restrict__ Rbf) {
  __shared__ float smem[8704];   // 34,816 B
  int t = threadIdx.x;
  int bid = blockIdx.x;
  if (bid >= 1280) {  // ---- Rbf: frag-order bf16 of exp(masked rules) ----
    int idx = ((bid - 1280) << 8) + t;       // [kst(64)][lane(64)][r(8)]
    int kst = idx >> 9, ln = (idx >> 3) & 63, r = idx & 7;
    int a = ln & 31;
    int kp = kst * 16 + ((ln >> 5) << 3) + r;   // k' = p*32+q
    float v = __expf(rs[a * 1024 + kp] + (rm[a * 1024 + kp] - 1.0f) * 1e10f);
    Rbf[idx] = (unsigned short)f2bf(v);
    return;
  }
  if (bid >= 1024) {  // ---- posnode + D ----
    float* rowl = smem;
    float* partl = smem + 1024;
    float* posn = smem + 1288;
    int row = bid - 1024;
#pragma unroll
    for (int k = 0; k < 4; ++k) rowl[t + 256 * k] = sh[row * 1024 + t + 256 * k];
    __syncthreads();
    int c = t & 31, seg = t >> 5;
    float pacc = 0.f;
    for (int hh = 0; hh < 128; ++hh)
      pacc += rowl[seg * 128 + hh] * Wp[(seg * 128 + hh) * 32 + c];
    partl[seg * 33 + c] = pacc;
    __syncthreads();
    if (t < 32) {
      float s = 0.f;
#pragma unroll
      for (int k = 0; k < 8; ++k) s += partl[k * 33 + t];
      posn[t] = s + bp[t] + (pmask[t] - 1.0f) * 1e10f;
    }
    __syncthreads();
    if (t < 32) {
      float mq = posn[t];
#pragma unroll
      for (int m = 16; m >= 1; m >>= 1) mq = fmaxf(mq, __shfl_xor(mq, m, 32));
      float sum = 0.f;
#pragma unroll 8
      for (int q = 0; q < 32; ++q)
        sum += __expf(pu[t * 32 + q] + (pum[t * 32 + q] - 1.0f) * 1e15f + posn[q] - mq);
      D[row * 32 + t] = mq + __logf(sum);
    }
    return;
  }
  // ---- node split-K GEMM via MFMA: 32 rows x 256 K per block ----
  unsigned short* As = (unsigned short*)smem;
  unsigned short* Wt = ((unsigned short*)smem) + 8448;
  float* Wsl = smem + 8448;
  float* slots = smem;
  int rg = bid >> 2, s = bid & 3;
  int row0 = rg << 5, k0 = s << 8;
#pragma unroll
  for (int u = 0; u < 8; ++u) {
    int idx = t + (u << 8);
    int r = idx >> 6, f4 = idx & 63;
    float4 v = *(const float4*)&ph[(row0 + r) * 1024 + k0 + (f4 << 2)];
    unsigned* dst = (unsigned*)(As + r * 264 + (f4 << 2));
    dst[0] = pk2bf(v.x, v.y);
    dst[1] = pk2bf(v.z, v.w);
  }
#pragma unroll
  for (int u = 0; u < 8; ++u) {
    int idx = t + (u << 8);
    int k = idx >> 3, c4 = idx & 7;
    float4 v = *(const float4*)&Wn[(k0 + k) * 32 + (c4 << 2)];
    int cb = c4 << 2;
    Wt[(cb + 0) * 264 + k] = hubf(v.x);
    Wt[(cb + 1) * 264 + k] = hubf(v.y);
    Wt[(cb + 2) * 264 + k] = hubf(v.z);
    Wt[(cb + 3) * 264 + k] = hubf(v.w);
  }
  if (t < 256) Wsl[t] = Ws[k0 + t];
  __syncthreads();
  int wv = t >> 6, ln2 = t & 63;
  int m31 = ln2 & 31, hi2 = ln2 >> 5;
  f32x16 C = {};
#pragma unroll
  for (int kc = 0; kc < 64; kc += 16) {
    int ko = (wv << 6) + kc + (hi2 << 3);
    bf16x8 af = *(const bf16x8*)(As + m31 * 264 + ko);
    bf16x8 bfv = *(const bf16x8*)(Wt + m31 * 264 + ko);
    C = __builtin_amdgcn_mfma_f32_32x32x16_bf16(af, bfv, C, 0, 0, 0);
  }
  float spn = 0.f;
  if (t < 32) {
#pragma unroll 4
    for (int kk = 0; kk < 256; kk += 8) {
      bf16x8 avv = *(const bf16x8*)(As + t * 264 + kk);
#pragma unroll
      for (int e = 0; e < 8; ++e)
        spn += bfup((unsigned short)avv[e]) * Wsl[kk + e];
    }
  }
  __syncthreads();
  float* sl = slots + (wv << 10);
#pragma unroll
  for (int rr = 0; rr < 16; ++rr) {
    int arow = (rr & 3) + ((rr >> 2) << 3) + (hi2 << 2);
    sl[arow * 32 + m31] = C[rr];
  }
  __syncthreads();
#pragma unroll
  for (int u = 0; u < 4; ++u) {
    int idx = t + (u << 8);
    part[s * 262144 + (row0 << 5) + idx] =
        slots[idx] + slots[1024 + idx] + slots[2048 + idx] + slots[3072 + idx];
  }
  if (t < 32) partS[s * 8192 + row0 + t] = spn;
}

// One block per batch; entry fuses the split-K reduce (own batch slice).
// Chart as NORMALIZED X = exp(cn - rowmax) in LDS (transposed, stride 529).
// Per stage (3 barriers): [prefetch + in-wave P1 (sc-only table) + P2 with
// IN-REGISTER incremental gather indices] B1 [P3 8-wave b128] B2 [out+renorm] B3
// LDS 161600 B:
//   Xt    f32[32*529]    @0
//   Sb    32 x 2064 B    @67712    (bf16 S, XOR-swizzled, 16B-aligned rows)
//   slotb u16[8][1088]   @133760   (bf16 P3 partials)
//   Tscl  f32[32*32]     @151168   (per-(cell,j) scale; rc computed in-reg)
//   maxv  f32[528]       @159360
//   G     f32[32]        @161472
__global__ __launch_bounds__(1024, 4) void k_chain9(
    const float* __restrict__ part, const float* __restrict__ partS,
    const float* __restrict__ bn, const float* __restrict__ bs,
    float* __restrict__ node, float* __restrict__ span,
    const float* __restrict__ D, const unsigned short* __restrict__ Rbf,
    const int* __restrict__ sm, const float* __restrict__ rootm,
    float* __restrict__ out) {
  extern __shared__ char lds[];
  float* Xt = (float*)lds;
  char* Sb = lds + 67712;
  unsigned short* slotb = (unsigned short*)(lds + 133760);
  float* Tscl = (float*)(lds + 151168);
  float* maxv = (float*)(lds + 159360);
  float* G = (float*)(lds + 161472);
  const int t = threadIdx.x;
  const int b = blockIdx.x;
  const int w = t >> 6, ln = t & 63;
  const int pq = ln & 31, hi = ln >> 5, jb = hi << 3;
  const int rowB = b * 32;

  // ---- persistent Rbf fragments (waves 0-7): 8 frags = 32 VGPRs each ----
  BFU rb[8];
  if (w < 8) {
#pragma unroll
    for (int tt = 0; tt < 8; ++tt)
      rb[tt].v = *(const bf16x8*)(Rbf + (((w << 3) + tt) << 9) + (ln << 3));
  }

  // ---- entry: fused split-K reduce for this batch (node, span) ----
  {
    int base = b << 15;
#pragma unroll
    for (int k = 0; k < 8; ++k) {
      int idx = t + (k << 10);
      float4 v0 = *(const float4*)&part[base + (idx << 2)];
      float4 v1 = *(const float4*)&part[262144 + base + (idx << 2)];
      float4 v2 = *(const float4*)&part[524288 + base + (idx << 2)];
      float4 v3 = *(const float4*)&part[786432 + base + (idx << 2)];
      float4 bb = *(const float4*)&bn[(idx << 2) & 31];
      *(float4*)&node[base + (idx << 2)] =
          make_float4(v0.x + v1.x + v2.x + v3.x + bb.x,
                      v0.y + v1.y + v2.y + v3.y + bb.y,
                      v0.z + v1.z + v2.z + v3.z + bb.z,
                      v0.w + v1.w + v2.w + v3.w + bb.w);
    }
    int row = (b << 10) + t;
    span[row] = bs[0] + partS[row] + partS[8192 + row] +
                partS[16384 + row] + partS[24576 + row];
    float* z = (float*)lds;
    for (int idx = t; idx < 16928; idx += 1024) z[idx] = 0.f;
  }
  __syncthreads();
  // ---- diagonal init from node & D ----
  {
    int l = t >> 5, a = t & 31;
    float nd = node[(b << 15) + (l << 10) + (l << 5) + a];
    float dv = nd + nd + D[(rowB + l) * 32 + a];
    float m = dv;
#pragma unroll
    for (int s = 16; s >= 1; s >>= 1) m = fmaxf(m, __shfl_xor(m, s, 32));
    int off = l * (65 - l) / 2;
    Xt[a * 529 + off] = __expf(dv - m);
    if (a == 0) maxv[off] = m;
  }
  __syncthreads();

  for (int i = 1; i < 32; ++i) {
    const int nT = 32 - i;
    float nv = 0.f, sv = 0.f;
    {
      int cell = t >> 5;
      if (cell < nT) {
        nv = node[(rowB + cell) * 1024 + (cell + i) * 32 + (t & 31)];
        sv = span[(rowB + cell) * 32 + (cell + i)];
      }
    }
    // ---- in-wave P1: lane (hi,pq) -> cell ct=hi?16+w:w, j=pq; store sc only ----
    {
      int ct = hi ? 16 + w : w;
      bool on = (ct < nT) && (pq < i);
      float gj = -3.0e38f;
      if (on) {
        int m2 = ct + pq + 1;
        int rc = m2 * (65 - m2) / 2 + (i - 1 - pq);
        gj = maxv[ct * (65 - ct) / 2 + pq] + maxv[rc];
      }
      float gm = gj;
#pragma unroll
      for (int s = 16; s >= 1; s >>= 1) gm = fmaxf(gm, __shfl_xor(gm, s, 32));
      if (ct < nT) {
        Tscl[(ct << 5) + pq] = on ? __expf(gj - gm) : 0.f;
        if (pq == 0) G[ct] = gm;
      }
    }
    // ---- P2: wave w -> cells w and 16+w; rc computed IN-REGISTER ----
#pragma unroll 1
    for (int half = 0; half < 2; ++half) {
      int cg = (half << 4) + w;
      if (cg >= nT) break;
      const float* xlb = Xt + pq * 529 + cg * (65 - cg) / 2;
      const float* xrr = Xt + pq * 529;
      const float* scb = Tscl + (cg << 5);
      f32x16 Sacc = {};
#pragma unroll
      for (int kk = 0; kk < 2; ++kk) {
        if (kk == 1 && i <= 16) break;
        int j0 = (kk << 4);
        int jB = j0 + jb;
        // in-register gather indices: rc(j) = T(m2)+(i-1-j), rc(j+1)=rc(j)+31-m2
        int m2 = cg + jB + 1;
        int rc = m2 * (65 - m2) / 2 + (i - 1 - jB);
        BFU ua, ub;
#pragma unroll
        for (int r2 = 0; r2 < 4; ++r2) {
          int j = jB + (r2 << 1);
          float x0 = xrr[rc]; rc += 31 - m2; ++m2;
          float x1 = xrr[rc]; rc += 31 - m2; ++m2;
          float s0 = scb[j], s1 = scb[j + 1];
          float a0 = xlb[j] * s0;
          float a1 = xlb[j + 1] * s1;
          ua.u[r2] = pk2bf(a0, a1);
          ub.u[r2] = pk2bf(x0, x1);
        }
        Sacc = __builtin_amdgcn_mfma_f32_32x32x16_bf16(ua.v, ub.v, Sacc, 0, 0, 0);
      }
      char* sbp = Sb + cg * 2064;
#pragma unroll
      for (int rr = 0; rr < 16; rr += 2) {
        unsigned pk = pk2bf(Sacc[rr], Sacc[rr + 1]);
        int p0 = (rr & 3) + ((rr >> 2) << 3) + (hi << 2);
        int sw = (((pq >> 3) & 1) << 4) ^ (((p0 >> 2) & 1) << 2);
        int wd0 = (((p0 << 4) + (pq >> 1)) ^ sw);
        int wd1 = wd0 ^ 16;
        *(unsigned short*)(sbp + wd0 * 4 + ((pq & 1) << 1)) = (unsigned short)pk;
        *(unsigned short*)(sbp + wd1 * 4 + ((pq & 1) << 1)) = (unsigned short)(pk >> 16);
      }
    }
    __syncthreads();   // B1
    // ---- P3: inner = R * S, 8-wave k-split; Sb frags via single b128 ----
    if (w < 8) {
      f32x16 C0 = {}, C1 = {};
#pragma unroll
      for (int tt = 0; tt < 8; ++tt) {
        int kst = (w << 3) + tt;
        int ko = (kst << 1) + hi;
        int p = ko >> 2, o = ko & 3;
        int wd = (((p << 4) + (o << 2)) ^ ((o & 1) << 4)) ^ (((p >> 2) & 1) << 2);
        const uint4* sp = (const uint4*)(Sb + pq * 2064 + wd * 4);
        BFU ub;
        *(uint4*)&ub.u[0] = *sp;
        if (tt & 1) C1 = __builtin_amdgcn_mfma_f32_32x32x16_bf16(rb[tt].v, ub.v, C1, 0, 0, 0);
        else        C0 = __builtin_amdgcn_mfma_f32_32x32x16_bf16(rb[tt].v, ub.v, C0, 0, 0, 0);
      }
      unsigned short* sl = slotb + w * 1088;
#pragma unroll
      for (int rr = 0; rr < 16; rr += 2) {
        int arow = (rr & 3) + ((rr >> 2) << 3) + (hi << 2);
        *(unsigned*)(sl + pq * 34 + arow) =
            pk2bf(C0[rr] + C1[rr], C0[rr + 1] + C1[rr + 1]);
      }
    }
    __syncthreads();   // B2
    // ---- out + renorm fused ----
    {
      int cell = t >> 5, a = t & 31;
      if (cell < nT) {
        int so = cell * 34 + a;
        float pt = 0.f;
#pragma unroll
        for (int k = 0; k < 8; ++k) pt += bfup(slotb[k * 1088 + so]);
        float cnv = G[cell] + __logf(pt) + nv + nv + sv;
        float m = cnv;
#pragma unroll
        for (int s = 16; s >= 1; s >>= 1) m = fmaxf(m, __shfl_xor(m, s, 32));
        int ix = cell * (65 - cell) / 2 + i;
        Xt[a * 529 + ix] = __expf(cnv - m);
        if (a == 0) maxv[ix] = m;
      }
    }
    __syncthreads();   // B3
  }
  // ---- logits ----
  if (t < 32) {
    int len = 0;
#pragma unroll
    for (int l = 0; l < 32; ++l) len += sm[b * 32 + l];
    int e = len - 1;
    float cv = maxv[e] + __logf(Xt[t * 529 + e]) - node[(rowB * 32 + e) * 32 + t];
    out[b * 32 + t] = cv + (rootm[t] - 1.0f) * 1e10f;
  }
}

extern "C" void kernel_launch(void* const* d_in, const int* in_sizes, int n_in,
                              void* d_out, int out_size, void* d_ws, size_t ws_size,
                              hipStream_t stream) {
  const float* ph    = (const float*)d_in[0];
  const float* sh    = (const float*)d_in[1];
  const int*   sm    = (const int*)  d_in[2];
  const float* Wp    = (const float*)d_in[3];
  const float* bp    = (const float*)d_in[4];
  const float* Wn    = (const float*)d_in[5];
  const float* bn    = (const float*)d_in[6];
  const float* Ws    = (const float*)d_in[7];
  const float* bs    = (const float*)d_in[8];
  const float* rs    = (const float*)d_in[9];
  const float* pu    = (const float*)d_in[10];
  const float* rootm = (const float*)d_in[11];
  const float* pm    = (const float*)d_in[12];
  const float* rm    = (const float*)d_in[13];
  const float* pum   = (const float*)d_in[14];
  float* out = (float*)d_out;

  float* ws    = (float*)d_ws;
  float* node  = ws + NODE_OFF;
  float* span  = ws + SPAN_OFF;
  float* D     = ws + D_OFF;
  unsigned short* Rbf = (unsigned short*)(ws + RBF_OFF);
  float* part  = ws + PART_OFF;
  float* partS = ws + PARTS_OFF;

  hipFuncSetAttribute((const void*)k_chain9,
                      hipFuncAttributeMaxDynamicSharedMemorySize, 161600);
  k_pre<<<1408, 256, 0, stream>>>(ph, Wn, Ws, sh, Wp, bp, pm, pu, pum, rs, rm,
                                  part, partS, D, Rbf);
  k_chain9<<<8, 1024, 161600, stream>>>(part, partS, bn, bs, node, span, D, Rbf,
                                        sm, rootm, out);
}